// Round 11
// baseline (303.580 us; speedup 1.0000x reference)
//
#include <hip/hip_runtime.h>
#include <hip/hip_bf16.h>
#include <hip/hip_fp8.h>

#define NEG 0.2f

typedef float floatx2 __attribute__((ext_vector_type(2)));

__device__ __forceinline__ float leaky(float v) { return v > 0.f ? v : NEG * v; }

__device__ __forceinline__ void unpack2(unsigned w, float& lo, float& hi) {
    union { unsigned u; float f; } a, b;
    a.u = w << 16;
    b.u = w & 0xffff0000u;
    lo = a.f; hi = b.f;
}

// ---------------- init ----------------
__global__ void zero_init(int* deg, float* pooled, float* counts, int n) {
    int i = blockIdx.x * blockDim.x + threadIdx.x;
    if (i < n) deg[i] = 0;
    if (i < 64 * 32) pooled[i] = 0.f;
    if (i < 64) counts[i] = 0.f;
}

// ---------------- CSR build ----------------
__global__ void count_edges(const int* __restrict__ ei, int E, int n, int* deg) {
    int i = blockIdx.x * blockDim.x + threadIdx.x;
    int tot = E + n;
    if (i < tot) {
        int dst = (i < E) ? ei[E + i] : (i - E);
        atomicAdd(&deg[dst], 1);
    }
}

// hierarchical scan, stage 1: per-block sum of deg + dinv (all coalesced)
__global__ void deg_dinv_bsum(const int* __restrict__ deg, float* __restrict__ dinv,
                              int* __restrict__ bsum, int n) {
    __shared__ int red[256];
    int t = threadIdx.x;
    int i = blockIdx.x * 256 + t;
    int d = (i < n) ? deg[i] : 0;
    if (i < n) dinv[i] = rsqrtf(fmaxf((float)d, 1.0f));
    red[t] = d;
    __syncthreads();
    for (int off = 128; off; off >>= 1) {
        if (t < off) red[t] += red[t + off];
        __syncthreads();
    }
    if (t == 0) bsum[blockIdx.x] = red[0];
}

// stage 2: exclusive scan of block sums (nb <= 256), writes rowptr[n]=total
__global__ void scan_bsum(const int* __restrict__ bsum, int* __restrict__ boff,
                          int* __restrict__ rowptr, int nb, int n) {
    __shared__ int s[256];
    int t = threadIdx.x;
    int own = (t < nb) ? bsum[t] : 0;
    s[t] = own;
    __syncthreads();
    for (int off = 1; off < 256; off <<= 1) {
        int v = (t >= off) ? s[t - off] : 0;
        __syncthreads();
        s[t] += v;
        __syncthreads();
    }
    if (t < nb) boff[t] = s[t] - own;
    if (t == 255) rowptr[n] = s[255];
}

// stage 3: in-block exclusive scan, writes rowptr/cursor coalesced
__global__ void write_rowptr(const int* __restrict__ deg, const int* __restrict__ boff,
                             int* __restrict__ rowptr, int* __restrict__ cursor, int n) {
    __shared__ int s[256];
    int t = threadIdx.x;
    int i = blockIdx.x * 256 + t;
    int d = (i < n) ? deg[i] : 0;
    s[t] = d;
    __syncthreads();
    for (int off = 1; off < 256; off <<= 1) {
        int v = (t >= off) ? s[t - off] : 0;
        __syncthreads();
        s[t] += v;
        __syncthreads();
    }
    if (i < n) {
        int r = boff[blockIdx.x] + s[t] - d;
        rowptr[i] = r;
        cursor[i] = r;
    }
}

__global__ void fill_edges(const int* __restrict__ ei, int E, int n, int* cursor, int* col) {
    int i = blockIdx.x * blockDim.x + threadIdx.x;
    int tot = E + n;
    if (i < tot) {
        int src, dst;
        if (i < E) { src = ei[i]; dst = ei[E + i]; }
        else { src = i - E; dst = i - E; }
        int pos = atomicAdd(&cursor[dst], 1);
        col[pos] = src;
    }
}

// ---------------- GAT1: x[N,32] @ W1[32,256]; h1 stored fp8 e4m3 ----
// 16 nodes per block; W1 read once per block (16x traffic cut).
__global__ void gat1_transform(const float* __restrict__ x, const float* __restrict__ W1,
                               const float* __restrict__ asr, const float* __restrict__ adt,
                               unsigned char* __restrict__ h1q, float* __restrict__ als,
                               float* __restrict__ ald, int n) {
    __shared__ float xr[16][32];
    int t = threadIdx.x;  // 256
    int base = blockIdx.x * 16;
    float w1r[32];
#pragma unroll
    for (int j = 0; j < 32; j++) w1r[j] = W1[j * 256 + t];
    if (t < 128) {  // 16 nodes x 32 ch = 128 float4
        int node = t >> 3;
        float4 v = make_float4(0.f, 0.f, 0.f, 0.f);
        if (base + node < n) v = ((const float4*)(x + (size_t)base * 32))[t];
        ((float4*)&xr[0][0])[t] = v;
    }
    __syncthreads();
    int head = t >> 6, lane = t & 63;
    float a_s = asr[t];
    float a_d = adt[t];
    for (int nn = 0; nn < 16; nn++) {
        int node = base + nn;
        float acc0 = 0.f, acc1 = 0.f, acc2 = 0.f, acc3 = 0.f;
#pragma unroll
        for (int j = 0; j < 32; j += 4) {
            acc0 += xr[nn][j]     * w1r[j];
            acc1 += xr[nn][j + 1] * w1r[j + 1];
            acc2 += xr[nn][j + 2] * w1r[j + 2];
            acc3 += xr[nn][j + 3] * w1r[j + 3];
        }
        float acc = (acc0 + acc1) + (acc2 + acc3);
        if (node < n) {
            __hip_fp8_e4m3 q(acc);
            h1q[(size_t)node * 256 + t] = (unsigned char)q.__x;
        }
        float ps = acc * a_s;
        float pd = acc * a_d;
#pragma unroll
        for (int off = 32; off; off >>= 1) {
            ps += __shfl_down(ps, off);
            pd += __shfl_down(pd, off);
        }
        if (node < n && lane == 0) { als[node * 4 + head] = ps; ald[node * 4 + head] = pd; }
    }
}

// one block per dst; wave w = head w
// fused single pass, fp8 gathers: 16 edges x 4 lanes x 16B (16 fp8 channels).
// wsum replicated across the 4 cl-lanes; xor-reduce over eg bits (4..32) counts
// each edge exactly once.
__global__ void gat1_aggregate(const unsigned char* __restrict__ h1q,
                               const float* __restrict__ als,
                               const float* __restrict__ ald, const int* __restrict__ rowptr,
                               const int* __restrict__ col, const float* __restrict__ b1,
                               float* __restrict__ out1, int n) {
    int dst = blockIdx.x;
    int head = threadIdx.x >> 6, lane = threadIdx.x & 63;
    int start = rowptr[dst], end = rowptr[dst + 1];
    float ad = ald[dst * 4 + head];

    int eg = lane >> 2;   // edge group 0..15
    int cl = lane & 3;    // 16B chunk (16 fp8 channels)
    float acc[16];
#pragma unroll
    for (int j = 0; j < 16; j++) acc[j] = 0.f;
    float wsum = 0.f;
    for (int ib = start; ib < end; ib += 16) {
        int i = ib + eg;
        float w = 0.f;
        int s = 0;
        if (i < end) {
            s = col[i];
            w = __expf(leaky(als[s * 4 + head] + ad));
        }
        wsum += w;
        uint4 hv = *((const uint4*)(h1q + (size_t)s * 256 + head * 64) + cl);
        floatx2 p0 = __builtin_amdgcn_cvt_pk_f32_fp8((int)hv.x, false);
        floatx2 p1 = __builtin_amdgcn_cvt_pk_f32_fp8((int)hv.x, true);
        floatx2 p2 = __builtin_amdgcn_cvt_pk_f32_fp8((int)hv.y, false);
        floatx2 p3 = __builtin_amdgcn_cvt_pk_f32_fp8((int)hv.y, true);
        floatx2 p4 = __builtin_amdgcn_cvt_pk_f32_fp8((int)hv.z, false);
        floatx2 p5 = __builtin_amdgcn_cvt_pk_f32_fp8((int)hv.z, true);
        floatx2 p6 = __builtin_amdgcn_cvt_pk_f32_fp8((int)hv.w, false);
        floatx2 p7 = __builtin_amdgcn_cvt_pk_f32_fp8((int)hv.w, true);
        acc[0]  += p0.x * w; acc[1]  += p0.y * w;
        acc[2]  += p1.x * w; acc[3]  += p1.y * w;
        acc[4]  += p2.x * w; acc[5]  += p2.y * w;
        acc[6]  += p3.x * w; acc[7]  += p3.y * w;
        acc[8]  += p4.x * w; acc[9]  += p4.y * w;
        acc[10] += p5.x * w; acc[11] += p5.y * w;
        acc[12] += p6.x * w; acc[13] += p6.y * w;
        acc[14] += p7.x * w; acc[15] += p7.y * w;
    }
#pragma unroll
    for (int off = 4; off <= 32; off <<= 1) {
        wsum += __shfl_xor(wsum, off);
#pragma unroll
        for (int j = 0; j < 16; j++) acc[j] += __shfl_xor(acc[j], off);
    }
    float inv = 1.0f / (wsum + 1e-16f);
    if (lane < 4) {
        const float* bb = b1 + head * 64 + cl * 16;
        float* op = out1 + (size_t)dst * 256 + head * 64 + cl * 16;
#pragma unroll
        for (int q = 0; q < 4; q++) {
            float4 o;
            o.x = fmaxf(acc[q * 4 + 0] * inv + bb[q * 4 + 0], 0.f);
            o.y = fmaxf(acc[q * 4 + 1] * inv + bb[q * 4 + 1], 0.f);
            o.z = fmaxf(acc[q * 4 + 2] * inv + bb[q * 4 + 2], 0.f);
            o.w = fmaxf(acc[q * 4 + 3] * inv + bb[q * 4 + 3], 0.f);
            ((float4*)op)[q] = o;
        }
    }
}

// ---------------- GAT2: out1[N,256] @ W2[256,64]; W2 K-slice cached in regs --
// __launch_bounds__(256, 2): without it the compiler caps VGPR at 64 and
// SPILLS w2r[64] to scratch -> 209 MB FETCH (R8/R9 regression).
__global__ void __launch_bounds__(256, 2)
gat2_transform(const float* __restrict__ xin, const float* __restrict__ W2,
               const float* __restrict__ asr, const float* __restrict__ adt,
               __hip_bfloat16* __restrict__ h2b, float* __restrict__ als,
               float* __restrict__ ald, int n) {
    __shared__ float xr[16][256];        // 16 KB
    __shared__ float part[4][16][64];    // 16 KB
    int t = threadIdx.x;
    int w = t >> 6, lane = t & 63;
    int base = blockIdx.x * 16;
    float w2r[64];
#pragma unroll
    for (int j = 0; j < 64; j++) w2r[j] = W2[(w * 64 + j) * 64 + lane];
    {
        const float4* src = (const float4*)(xin + (size_t)base * 256);
        float4* dst = (float4*)&xr[0][0];
        for (int i = t; i < 16 * 64; i += 256) {  // 1024 float4
            int node = i >> 6;
            float4 v = make_float4(0.f, 0.f, 0.f, 0.f);
            if (base + node < n) v = src[i];
            dst[i] = v;
        }
    }
    __syncthreads();
    for (int nn = 0; nn < 16; nn++) {
        const float* xrow = &xr[nn][w * 64];
        float a0 = 0.f, a1 = 0.f, a2 = 0.f, a3 = 0.f;
#pragma unroll
        for (int j = 0; j < 64; j += 16) {
            float4 v0 = *(const float4*)(xrow + j);
            float4 v1 = *(const float4*)(xrow + j + 4);
            float4 v2 = *(const float4*)(xrow + j + 8);
            float4 v3 = *(const float4*)(xrow + j + 12);
            a0 += v0.x * w2r[j]      + v0.y * w2r[j + 1]  + v0.z * w2r[j + 2]  + v0.w * w2r[j + 3];
            a1 += v1.x * w2r[j + 4]  + v1.y * w2r[j + 5]  + v1.z * w2r[j + 6]  + v1.w * w2r[j + 7];
            a2 += v2.x * w2r[j + 8]  + v2.y * w2r[j + 9]  + v2.z * w2r[j + 10] + v2.w * w2r[j + 11];
            a3 += v3.x * w2r[j + 12] + v3.y * w2r[j + 13] + v3.z * w2r[j + 14] + v3.w * w2r[j + 15];
        }
        part[w][nn][lane] = (a0 + a1) + (a2 + a3);
    }
    __syncthreads();
    float a_s = asr[lane], a_d = adt[lane];
    for (int q = 0; q < 4; q++) {
        int nn = w * 4 + q;
        int node = base + nn;
        float sum = (part[0][nn][lane] + part[1][nn][lane]) +
                    (part[2][nn][lane] + part[3][nn][lane]);
        if (node < n) h2b[(size_t)node * 64 + lane] = __float2bfloat16(sum);
        float ps = sum * a_s;
        float pd = sum * a_d;
#pragma unroll
        for (int off = 32; off; off >>= 1) {
            ps += __shfl_down(ps, off);
            pd += __shfl_down(pd, off);
        }
        if (node < n && lane == 0) { als[node] = ps; ald[node] = pd; }
    }
}

// wave per dst; SINGLE fused pass (bf16 gathers; h2b table is L2-resident)
__global__ void gat2_aggregate(const unsigned short* __restrict__ h2b,
                               const float* __restrict__ als,
                               const float* __restrict__ ald, const int* __restrict__ rowptr,
                               const int* __restrict__ col, const float* __restrict__ b2,
                               float* __restrict__ h2f, int n) {
    int w = threadIdx.x >> 6, lane = threadIdx.x & 63;
    int dst = blockIdx.x * 4 + w;
    if (dst >= n) return;
    float ad = ald[dst];
    int start = rowptr[dst], end = rowptr[dst + 1];

    int eg = lane >> 3;
    int cl = lane & 7;
    float acc[8];
#pragma unroll
    for (int j = 0; j < 8; j++) acc[j] = 0.f;
    float wsum = 0.f;
    for (int ib = start; ib < end; ib += 8) {
        int i = ib + eg;
        float wv = 0.f;
        int s = 0;
        if (i < end) {
            s = col[i];
            wv = __expf(leaky(als[s] + ad));
        }
        wsum += wv;
        uint4 hv = *((const uint4*)(h2b + (size_t)s * 64) + cl);
        float l0, u0, l1, u1, l2, u2, l3, u3;
        unpack2(hv.x, l0, u0); unpack2(hv.y, l1, u1);
        unpack2(hv.z, l2, u2); unpack2(hv.w, l3, u3);
        acc[0] += l0 * wv; acc[1] += u0 * wv;
        acc[2] += l1 * wv; acc[3] += u1 * wv;
        acc[4] += l2 * wv; acc[5] += u2 * wv;
        acc[6] += l3 * wv; acc[7] += u3 * wv;
    }
#pragma unroll
    for (int off = 8; off <= 32; off <<= 1) {
        wsum += __shfl_xor(wsum, off);
#pragma unroll
        for (int j = 0; j < 8; j++) acc[j] += __shfl_xor(acc[j], off);
    }
    float inv = 1.0f / (wsum + 1e-16f);
    if (lane < 8) {
        float4 o0, o1;
        const float* bb = b2 + cl * 8;
        o0.x = fmaxf(acc[0] * inv + bb[0], 0.f);
        o0.y = fmaxf(acc[1] * inv + bb[1], 0.f);
        o0.z = fmaxf(acc[2] * inv + bb[2], 0.f);
        o0.w = fmaxf(acc[3] * inv + bb[3], 0.f);
        o1.x = fmaxf(acc[4] * inv + bb[4], 0.f);
        o1.y = fmaxf(acc[5] * inv + bb[5], 0.f);
        o1.z = fmaxf(acc[6] * inv + bb[6], 0.f);
        o1.w = fmaxf(acc[7] * inv + bb[7], 0.f);
        float4* op = (float4*)(h2f + (size_t)dst * 64 + cl * 8);
        op[0] = o0; op[1] = o1;
    }
}

// ---------------- GCN: h2f[N,64] @ Wg[64,32] ----------------
__global__ void gcn_transform(const float* __restrict__ h2f, const float* __restrict__ Wg,
                              float* __restrict__ h3, int n) {
    int idx = blockIdx.x * blockDim.x + threadIdx.x;
    if (idx >= n * 32) return;
    int node = idx >> 5, c = idx & 31;
    float acc = 0.f;
#pragma unroll 8
    for (int k = 0; k < 64; k++) acc += h2f[node * 64 + k] * Wg[k * 32 + c];
    h3[idx] = acc;
}

// wave per dst; accumulate: 8 edges x 8 lanes x float4 (32 ch)
__global__ void gcn_aggregate(const float* __restrict__ h3, const float* __restrict__ dinv,
                              const int* __restrict__ rowptr, const int* __restrict__ col,
                              const float* __restrict__ bg, float* __restrict__ h4, int n) {
    int w = threadIdx.x >> 6, lane = threadIdx.x & 63;
    int dst = blockIdx.x * 4 + w;
    if (dst >= n) return;
    float dd = dinv[dst];
    int start = rowptr[dst], end = rowptr[dst + 1];
    int eg = lane >> 3;  // 0..7
    int cl = lane & 7;   // float4 chunk of 32 channels
    float4 acc = make_float4(0.f, 0.f, 0.f, 0.f);
    for (int ib = start; ib < end; ib += 8) {
        int i = ib + eg;
        float nrm = 0.f;
        int s = 0;
        if (i < end) {
            s = col[i];
            nrm = dinv[s];
        }
        float4 hv = ((const float4*)(h3 + (size_t)s * 32))[cl];
        acc.x += hv.x * nrm; acc.y += hv.y * nrm;
        acc.z += hv.z * nrm; acc.w += hv.w * nrm;
    }
#pragma unroll
    for (int off = 8; off <= 32; off <<= 1) {
        acc.x += __shfl_xor(acc.x, off);
        acc.y += __shfl_xor(acc.y, off);
        acc.z += __shfl_xor(acc.z, off);
        acc.w += __shfl_xor(acc.w, off);
    }
    if (lane < 8) {
        float4 bb = ((const float4*)bg)[cl];
        float4 o;
        o.x = fmaxf(acc.x * dd + bb.x, 0.f);
        o.y = fmaxf(acc.y * dd + bb.y, 0.f);
        o.z = fmaxf(acc.z * dd + bb.z, 0.f);
        o.w = fmaxf(acc.w * dd + bb.w, 0.f);
        ((float4*)(h4 + (size_t)dst * 32))[cl] = o;
    }
}

// ---------------- pooling: block-private LDS partials, sparse flush ----------------
__global__ void pool_kernel(const float* __restrict__ h4, const int* __restrict__ batch,
                            float* pooled, float* counts, int n) {
    __shared__ float part[64 * 32];
    __shared__ float pcnt[64];
    int t = threadIdx.x;  // 256
    for (int i = t; i < 64 * 32; i += 256) part[i] = 0.f;
    if (t < 64) pcnt[t] = 0.f;
    __syncthreads();
    int chunk = (n + gridDim.x - 1) / gridDim.x;
    int begin = blockIdx.x * chunk;
    int end = begin + chunk; if (end > n) end = n;
    int c = t & 31, r = t >> 5;  // 8 node-rows per iteration
    for (int node = begin + r; node < end; node += 8) {
        int g = batch[node];
        atomicAdd(&part[g * 32 + c], h4[(size_t)node * 32 + c]);
        if (c == 0) atomicAdd(&pcnt[g], 1.0f);
    }
    __syncthreads();
    for (int i = t; i < 64 * 32; i += 256) {
        float v = part[i];
        if (v != 0.f) atomicAdd(&pooled[i], v);
    }
    if (t < 64) {
        float v = pcnt[t];
        if (v != 0.f) atomicAdd(&counts[t], v);
    }
}

// ---------------- head: pooled -> anomaly[64] + emb[64,64] ----------------
__global__ void head_kernel(const float* __restrict__ pooled_s, const float* __restrict__ counts,
                            const float* __restrict__ A1, const float* __restrict__ ba1,
                            const float* __restrict__ A2, const float* __restrict__ ba2,
                            const float* __restrict__ A3, const float* __restrict__ ba3,
                            const float* __restrict__ Wemb, const float* __restrict__ bemb,
                            float* __restrict__ out) {
    __shared__ float P[64 * 32];
    __shared__ float Z1[64 * 32];
    __shared__ float Z2[64 * 16];
    int t = threadIdx.x;  // 256
    for (int i = t; i < 64 * 32; i += 256) {
        int g = i >> 5;
        P[i] = pooled_s[i] / fmaxf(counts[g], 1.0f);
    }
    __syncthreads();
    for (int i = t; i < 64 * 32; i += 256) {
        int g = i >> 5, c = i & 31;
        float a = ba1[c];
#pragma unroll
        for (int k = 0; k < 32; k++) a += P[g * 32 + k] * A1[k * 32 + c];
        Z1[i] = a > 0.f ? a : 0.f;
    }
    __syncthreads();
    for (int i = t; i < 64 * 16; i += 256) {
        int g = i >> 4, c = i & 15;
        float a = ba2[c];
#pragma unroll
        for (int k = 0; k < 32; k++) a += Z1[g * 32 + k] * A2[k * 16 + c];
        Z2[i] = a > 0.f ? a : 0.f;
    }
    __syncthreads();
    for (int g = t; g < 64; g += 256) {
        float a = ba3[0];
#pragma unroll
        for (int k = 0; k < 16; k++) a += Z2[g * 16 + k] * A3[k];
        out[g] = 1.0f / (1.0f + expf(-a));
    }
    for (int i = t; i < 64 * 64; i += 256) {
        int g = i >> 6, c = i & 63;
        float a = bemb[c];
#pragma unroll
        for (int k = 0; k < 32; k++) a += P[g * 32 + k] * Wemb[k * 64 + c];
        out[64 + i] = tanhf(a);
    }
}

extern "C" void kernel_launch(void* const* d_in, const int* in_sizes, int n_in,
                              void* d_out, int out_size, void* d_ws, size_t ws_size,
                              hipStream_t stream) {
    const float* x    = (const float*)d_in[0];
    const int*   ei   = (const int*)d_in[1];
    const int*   batch= (const int*)d_in[2];
    const float* W1   = (const float*)d_in[3];
    const float* as1  = (const float*)d_in[4];
    const float* ad1  = (const float*)d_in[5];
    const float* b1   = (const float*)d_in[6];
    const float* W2   = (const float*)d_in[7];
    const float* as2  = (const float*)d_in[8];
    const float* ad2  = (const float*)d_in[9];
    const float* b2   = (const float*)d_in[10];
    const float* Wg   = (const float*)d_in[11];
    const float* bg   = (const float*)d_in[12];
    const float* A1   = (const float*)d_in[13];
    const float* ba1  = (const float*)d_in[14];
    const float* A2   = (const float*)d_in[15];
    const float* ba2  = (const float*)d_in[16];
    const float* A3   = (const float*)d_in[17];
    const float* ba3  = (const float*)d_in[18];
    const float* Wemb = (const float*)d_in[19];
    const float* bemb = (const float*)d_in[20];
    float* out = (float*)d_out;

    const int N = in_sizes[0] / 32;
    const int E = in_sizes[1] / 2;
    const int ET = E + N;

    // workspace layout
    char* base = (char*)d_ws;
    size_t off = 0;
    auto take = [&](size_t bytes) -> char* {
        char* p = base + off;
        off = (off + bytes + 255) & ~(size_t)255;
        return p;
    };
    int*   deg    = (int*)take((size_t)N * 4);
    int*   rowptr = (int*)take((size_t)(N + 1) * 4);
    int*   cursor = (int*)take((size_t)N * 4);
    int*   col    = (int*)take((size_t)ET * 4);
    float* dinv   = (float*)take((size_t)N * 4);
    float* als1   = (float*)take((size_t)N * 16);
    float* ald1   = (float*)take((size_t)N * 16);
    int*   bsum   = (int*)take(256 * 4);
    int*   boff   = (int*)take(256 * 4);
    char*  big1   = take((size_t)N * 512);       // h1q fp8; later h2b/h2f/als2/ald2
    char*  big2   = take((size_t)N * 1024);      // out1 fp32; later h3/h4
    float* pooled = (float*)take(64 * 32 * 4);
    float* counts = (float*)take(64 * 4);

    unsigned char* h1q = (unsigned char*)big1;         // N*256 bytes
    float* out1 = (float*)big2;                        // N*1024 bytes

    // after gat1_aggregate, big1 is reused:
    __hip_bfloat16* h2b = (__hip_bfloat16*)big1;                 // N*128 B
    float* h2f  = (float*)(big1 + (size_t)N * 128);              // N*256 B
    float* als2 = (float*)(big1 + (size_t)N * 384);              // N*4 B
    float* ald2 = (float*)(big1 + (size_t)N * 388);              // N*4 B
    // after gat2_transform, big2 (out1) is reused:
    float* h3   = (float*)big2;                                  // N*128 B
    float* h4   = (float*)(big2 + (size_t)N * 128);              // N*128 B

    int gN = (N + 255) / 256;   // 79 for N=20000 (fits scan_bsum's 256 capacity)
    int gE = (ET + 255) / 256;
    int gN4 = (N + 3) / 4;
    int gN16 = (N + 15) / 16;

    zero_init<<<gN, 256, 0, stream>>>(deg, pooled, counts, N);
    count_edges<<<gE, 256, 0, stream>>>(ei, E, N, deg);
    deg_dinv_bsum<<<gN, 256, 0, stream>>>(deg, dinv, bsum, N);
    scan_bsum<<<1, 256, 0, stream>>>(bsum, boff, rowptr, gN, N);
    write_rowptr<<<gN, 256, 0, stream>>>(deg, boff, rowptr, cursor, N);
    fill_edges<<<gE, 256, 0, stream>>>(ei, E, N, cursor, col);

    gat1_transform<<<gN16, 256, 0, stream>>>(x, W1, as1, ad1, h1q, als1, ald1, N);
    gat1_aggregate<<<N, 256, 0, stream>>>(h1q, als1, ald1, rowptr, col, b1, out1, N);

    gat2_transform<<<gN16, 256, 0, stream>>>(out1, W2, as2, ad2, h2b, als2, ald2, N);
    gat2_aggregate<<<gN4, 256, 0, stream>>>((const unsigned short*)h2b, als2, ald2,
                                            rowptr, col, b2, h2f, N);

    gcn_transform<<<(N * 32 + 255) / 256, 256, 0, stream>>>(h2f, Wg, h3, N);
    gcn_aggregate<<<gN4, 256, 0, stream>>>(h3, dinv, rowptr, col, bg, h4, N);
    pool_kernel<<<256, 256, 0, stream>>>(h4, batch, pooled, counts, N);

    head_kernel<<<1, 256, 0, stream>>>(pooled, counts, A1, ba1, A2, ba2, A3, ba3,
                                       Wemb, bemb, out);
}

// Round 12
// 290.955 us; speedup vs baseline: 1.0434x; 1.0434x over previous
//
#include <hip/hip_runtime.h>
#include <hip/hip_bf16.h>

#define NEG 0.2f

__device__ __forceinline__ float leaky(float v) { return v > 0.f ? v : NEG * v; }

__device__ __forceinline__ void unpack2(unsigned w, float& lo, float& hi) {
    union { unsigned u; float f; } a, b;
    a.u = w << 16;
    b.u = w & 0xffff0000u;
    lo = a.f; hi = b.f;
}

// ---------------- init ----------------
__global__ void zero_init(int* deg, float* pooled, float* counts, int n) {
    int i = blockIdx.x * blockDim.x + threadIdx.x;
    if (i < n) deg[i] = 0;
    if (i < 64 * 32) pooled[i] = 0.f;
    if (i < 64) counts[i] = 0.f;
}

// ---------------- CSR build ----------------
__global__ void count_edges(const int* __restrict__ ei, int E, int n, int* deg) {
    int i = blockIdx.x * blockDim.x + threadIdx.x;
    int tot = E + n;
    if (i < tot) {
        int dst = (i < E) ? ei[E + i] : (i - E);
        atomicAdd(&deg[dst], 1);
    }
}

__global__ void deg_dinv_bsum(const int* __restrict__ deg, float* __restrict__ dinv,
                              int* __restrict__ bsum, int n) {
    __shared__ int red[256];
    int t = threadIdx.x;
    int i = blockIdx.x * 256 + t;
    int d = (i < n) ? deg[i] : 0;
    if (i < n) dinv[i] = rsqrtf(fmaxf((float)d, 1.0f));
    red[t] = d;
    __syncthreads();
    for (int off = 128; off; off >>= 1) {
        if (t < off) red[t] += red[t + off];
        __syncthreads();
    }
    if (t == 0) bsum[blockIdx.x] = red[0];
}

__global__ void scan_bsum(const int* __restrict__ bsum, int* __restrict__ boff,
                          int* __restrict__ rowptr, int nb, int n) {
    __shared__ int s[256];
    int t = threadIdx.x;
    int own = (t < nb) ? bsum[t] : 0;
    s[t] = own;
    __syncthreads();
    for (int off = 1; off < 256; off <<= 1) {
        int v = (t >= off) ? s[t - off] : 0;
        __syncthreads();
        s[t] += v;
        __syncthreads();
    }
    if (t < nb) boff[t] = s[t] - own;
    if (t == 255) rowptr[n] = s[255];
}

__global__ void write_rowptr(const int* __restrict__ deg, const int* __restrict__ boff,
                             int* __restrict__ rowptr, int* __restrict__ cursor, int n) {
    __shared__ int s[256];
    int t = threadIdx.x;
    int i = blockIdx.x * 256 + t;
    int d = (i < n) ? deg[i] : 0;
    s[t] = d;
    __syncthreads();
    for (int off = 1; off < 256; off <<= 1) {
        int v = (t >= off) ? s[t - off] : 0;
        __syncthreads();
        s[t] += v;
        __syncthreads();
    }
    if (i < n) {
        int r = boff[blockIdx.x] + s[t] - d;
        rowptr[i] = r;
        cursor[i] = r;
    }
}

// runs AFTER gat1_transform: also precomputes per-edge GAT1 softmax weights
// (4 heads) and the edge's dst — removes the als-gather + exp from the
// latency-critical dst-side aggregate loop.
__global__ void fill_edges(const int* __restrict__ ei, int E, int n, int* cursor,
                           int* __restrict__ col, int* __restrict__ edst,
                           float* __restrict__ ew4,
                           const float* __restrict__ als1, const float* __restrict__ ald1) {
    int i = blockIdx.x * blockDim.x + threadIdx.x;
    int tot = E + n;
    if (i < tot) {
        int src, dst;
        if (i < E) { src = ei[i]; dst = ei[E + i]; }
        else { src = i - E; dst = i - E; }
        int pos = atomicAdd(&cursor[dst], 1);
        col[pos] = src;
        edst[pos] = dst;
        float4 as = ((const float4*)als1)[src];
        float4 ad = ((const float4*)ald1)[dst];
        float4 w;
        w.x = __expf(leaky(as.x + ad.x));
        w.y = __expf(leaky(as.y + ad.y));
        w.z = __expf(leaky(as.z + ad.z));
        w.w = __expf(leaky(as.w + ad.w));
        ((float4*)ew4)[pos] = w;
    }
}

// after gat2_transform: per-edge GAT2 weight + fused GCN norm
__global__ void edge_w2(const int* __restrict__ col, const int* __restrict__ edst,
                        const float* __restrict__ als2, const float* __restrict__ ald2,
                        const float* __restrict__ dinv,
                        float* __restrict__ ew2, float* __restrict__ ewg, int et) {
    int i = blockIdx.x * blockDim.x + threadIdx.x;
    if (i < et) {
        int s = col[i], d = edst[i];
        ew2[i] = __expf(leaky(als2[s] + ald2[d]));
        ewg[i] = dinv[s] * dinv[d];
    }
}

// ---------------- GAT1: x[N,32] @ W1[32,256]; h1 stored bf16 ----
__global__ void gat1_transform(const float* __restrict__ x, const float* __restrict__ W1,
                               const float* __restrict__ asr, const float* __restrict__ adt,
                               __hip_bfloat16* __restrict__ h1b, float* __restrict__ als,
                               float* __restrict__ ald, int n) {
    __shared__ float xr[16][32];
    int t = threadIdx.x;  // 256
    int base = blockIdx.x * 16;
    float w1r[32];
#pragma unroll
    for (int j = 0; j < 32; j++) w1r[j] = W1[j * 256 + t];
    if (t < 128) {
        int node = t >> 3;
        float4 v = make_float4(0.f, 0.f, 0.f, 0.f);
        if (base + node < n) v = ((const float4*)(x + (size_t)base * 32))[t];
        ((float4*)&xr[0][0])[t] = v;
    }
    __syncthreads();
    int head = t >> 6, lane = t & 63;
    float a_s = asr[t];
    float a_d = adt[t];
    for (int nn = 0; nn < 16; nn++) {
        int node = base + nn;
        float acc0 = 0.f, acc1 = 0.f, acc2 = 0.f, acc3 = 0.f;
#pragma unroll
        for (int j = 0; j < 32; j += 4) {
            acc0 += xr[nn][j]     * w1r[j];
            acc1 += xr[nn][j + 1] * w1r[j + 1];
            acc2 += xr[nn][j + 2] * w1r[j + 2];
            acc3 += xr[nn][j + 3] * w1r[j + 3];
        }
        float acc = (acc0 + acc1) + (acc2 + acc3);
        if (node < n) h1b[(size_t)node * 256 + t] = __float2bfloat16(acc);
        float ps = acc * a_s;
        float pd = acc * a_d;
#pragma unroll
        for (int off = 32; off; off >>= 1) {
            ps += __shfl_down(ps, off);
            pd += __shfl_down(pd, off);
        }
        if (node < n && lane == 0) { als[node * 4 + head] = ps; ald[node * 4 + head] = pd; }
    }
}

// one block per dst; wave w = head w; 8 edges x 8 lanes x 16B (8 bf16).
// Weights precomputed in ew4 — chain depth 1 (col[i] -> h1b gather).
// wsum replicated across cl-lanes; xor-reduce over eg bits only — no /8.
__global__ void gat1_aggregate(const unsigned short* __restrict__ h1b,
                               const float* __restrict__ ew4,
                               const int* __restrict__ rowptr,
                               const int* __restrict__ col, const float* __restrict__ b1,
                               float* __restrict__ out1, int n) {
    int dst = blockIdx.x;
    int head = threadIdx.x >> 6, lane = threadIdx.x & 63;
    int start = rowptr[dst], end = rowptr[dst + 1];

    int eg = lane >> 3;
    int cl = lane & 7;
    float acc[8];
#pragma unroll
    for (int j = 0; j < 8; j++) acc[j] = 0.f;
    float wsum = 0.f;
    for (int ib = start; ib < end; ib += 8) {
        int i = ib + eg;
        float w = 0.f;
        int s = 0;
        if (i < end) {
            s = col[i];
            w = ew4[i * 4 + head];
        }
        wsum += w;
        uint4 hv = *((const uint4*)(h1b + (size_t)s * 256 + head * 64) + cl);
        float l0, u0, l1, u1, l2, u2, l3, u3;
        unpack2(hv.x, l0, u0); unpack2(hv.y, l1, u1);
        unpack2(hv.z, l2, u2); unpack2(hv.w, l3, u3);
        acc[0] += l0 * w; acc[1] += u0 * w;
        acc[2] += l1 * w; acc[3] += u1 * w;
        acc[4] += l2 * w; acc[5] += u2 * w;
        acc[6] += l3 * w; acc[7] += u3 * w;
    }
#pragma unroll
    for (int off = 8; off <= 32; off <<= 1) {
        wsum += __shfl_xor(wsum, off);
#pragma unroll
        for (int j = 0; j < 8; j++) acc[j] += __shfl_xor(acc[j], off);
    }
    float inv = 1.0f / (wsum + 1e-16f);
    if (lane < 8) {
        float4 o0, o1;
        const float* bb = b1 + head * 64 + cl * 8;
        o0.x = fmaxf(acc[0] * inv + bb[0], 0.f);
        o0.y = fmaxf(acc[1] * inv + bb[1], 0.f);
        o0.z = fmaxf(acc[2] * inv + bb[2], 0.f);
        o0.w = fmaxf(acc[3] * inv + bb[3], 0.f);
        o1.x = fmaxf(acc[4] * inv + bb[4], 0.f);
        o1.y = fmaxf(acc[5] * inv + bb[5], 0.f);
        o1.z = fmaxf(acc[6] * inv + bb[6], 0.f);
        o1.w = fmaxf(acc[7] * inv + bb[7], 0.f);
        float4* op = (float4*)(out1 + (size_t)dst * 256 + head * 64 + cl * 8);
        op[0] = o0; op[1] = o1;
    }
}

// ---------------- GAT2 transform: W2 K-slice cached in regs --
// __launch_bounds__(256, 2): without it the compiler caps VGPR at 64 and
// SPILLS w2r[64] to scratch -> 209 MB FETCH (R8/R9 regression).
__global__ void __launch_bounds__(256, 2)
gat2_transform(const float* __restrict__ xin, const float* __restrict__ W2,
               const float* __restrict__ asr, const float* __restrict__ adt,
               __hip_bfloat16* __restrict__ h2b, float* __restrict__ als,
               float* __restrict__ ald, int n) {
    __shared__ float xr[16][256];
    __shared__ float part[4][16][64];
    int t = threadIdx.x;
    int w = t >> 6, lane = t & 63;
    int base = blockIdx.x * 16;
    float w2r[64];
#pragma unroll
    for (int j = 0; j < 64; j++) w2r[j] = W2[(w * 64 + j) * 64 + lane];
    {
        const float4* src = (const float4*)(xin + (size_t)base * 256);
        float4* dst = (float4*)&xr[0][0];
        for (int i = t; i < 16 * 64; i += 256) {
            int node = i >> 6;
            float4 v = make_float4(0.f, 0.f, 0.f, 0.f);
            if (base + node < n) v = src[i];
            dst[i] = v;
        }
    }
    __syncthreads();
    for (int nn = 0; nn < 16; nn++) {
        const float* xrow = &xr[nn][w * 64];
        float a0 = 0.f, a1 = 0.f, a2 = 0.f, a3 = 0.f;
#pragma unroll
        for (int j = 0; j < 64; j += 16) {
            float4 v0 = *(const float4*)(xrow + j);
            float4 v1 = *(const float4*)(xrow + j + 4);
            float4 v2 = *(const float4*)(xrow + j + 8);
            float4 v3 = *(const float4*)(xrow + j + 12);
            a0 += v0.x * w2r[j]      + v0.y * w2r[j + 1]  + v0.z * w2r[j + 2]  + v0.w * w2r[j + 3];
            a1 += v1.x * w2r[j + 4]  + v1.y * w2r[j + 5]  + v1.z * w2r[j + 6]  + v1.w * w2r[j + 7];
            a2 += v2.x * w2r[j + 8]  + v2.y * w2r[j + 9]  + v2.z * w2r[j + 10] + v2.w * w2r[j + 11];
            a3 += v3.x * w2r[j + 12] + v3.y * w2r[j + 13] + v3.z * w2r[j + 14] + v3.w * w2r[j + 15];
        }
        part[w][nn][lane] = (a0 + a1) + (a2 + a3);
    }
    __syncthreads();
    float a_s = asr[lane], a_d = adt[lane];
    for (int q = 0; q < 4; q++) {
        int nn = w * 4 + q;
        int node = base + nn;
        float sum = (part[0][nn][lane] + part[1][nn][lane]) +
                    (part[2][nn][lane] + part[3][nn][lane]);
        if (node < n) h2b[(size_t)node * 64 + lane] = __float2bfloat16(sum);
        float ps = sum * a_s;
        float pd = sum * a_d;
#pragma unroll
        for (int off = 32; off; off >>= 1) {
            ps += __shfl_down(ps, off);
            pd += __shfl_down(pd, off);
        }
        if (node < n && lane == 0) { als[node] = ps; ald[node] = pd; }
    }
}

// wave per dst; weights precomputed in ew2
__global__ void gat2_aggregate(const unsigned short* __restrict__ h2b,
                               const float* __restrict__ ew2,
                               const int* __restrict__ rowptr,
                               const int* __restrict__ col, const float* __restrict__ b2,
                               float* __restrict__ h2f, int n) {
    int w = threadIdx.x >> 6, lane = threadIdx.x & 63;
    int dst = blockIdx.x * 4 + w;
    if (dst >= n) return;
    int start = rowptr[dst], end = rowptr[dst + 1];

    int eg = lane >> 3;
    int cl = lane & 7;
    float acc[8];
#pragma unroll
    for (int j = 0; j < 8; j++) acc[j] = 0.f;
    float wsum = 0.f;
    for (int ib = start; ib < end; ib += 8) {
        int i = ib + eg;
        float wv = 0.f;
        int s = 0;
        if (i < end) {
            s = col[i];
            wv = ew2[i];
        }
        wsum += wv;
        uint4 hv = *((const uint4*)(h2b + (size_t)s * 64) + cl);
        float l0, u0, l1, u1, l2, u2, l3, u3;
        unpack2(hv.x, l0, u0); unpack2(hv.y, l1, u1);
        unpack2(hv.z, l2, u2); unpack2(hv.w, l3, u3);
        acc[0] += l0 * wv; acc[1] += u0 * wv;
        acc[2] += l1 * wv; acc[3] += u1 * wv;
        acc[4] += l2 * wv; acc[5] += u2 * wv;
        acc[6] += l3 * wv; acc[7] += u3 * wv;
    }
#pragma unroll
    for (int off = 8; off <= 32; off <<= 1) {
        wsum += __shfl_xor(wsum, off);
#pragma unroll
        for (int j = 0; j < 8; j++) acc[j] += __shfl_xor(acc[j], off);
    }
    float inv = 1.0f / (wsum + 1e-16f);
    if (lane < 8) {
        float4 o0, o1;
        const float* bb = b2 + cl * 8;
        o0.x = fmaxf(acc[0] * inv + bb[0], 0.f);
        o0.y = fmaxf(acc[1] * inv + bb[1], 0.f);
        o0.z = fmaxf(acc[2] * inv + bb[2], 0.f);
        o0.w = fmaxf(acc[3] * inv + bb[3], 0.f);
        o1.x = fmaxf(acc[4] * inv + bb[4], 0.f);
        o1.y = fmaxf(acc[5] * inv + bb[5], 0.f);
        o1.z = fmaxf(acc[6] * inv + bb[6], 0.f);
        o1.w = fmaxf(acc[7] * inv + bb[7], 0.f);
        float4* op = (float4*)(h2f + (size_t)dst * 64 + cl * 8);
        op[0] = o0; op[1] = o1;
    }
}

// ---------------- GCN: h2f[N,64] @ Wg[64,32] ----------------
__global__ void gcn_transform(const float* __restrict__ h2f, const float* __restrict__ Wg,
                              float* __restrict__ h3, int n) {
    int idx = blockIdx.x * blockDim.x + threadIdx.x;
    if (idx >= n * 32) return;
    int node = idx >> 5, c = idx & 31;
    float acc = 0.f;
#pragma unroll 8
    for (int k = 0; k < 64; k++) acc += h2f[node * 64 + k] * Wg[k * 32 + c];
    h3[idx] = acc;
}

// wave per dst; full edge norm precomputed in ewg (dinv[s]*dinv[d])
__global__ void gcn_aggregate(const float* __restrict__ h3, const float* __restrict__ ewg,
                              const int* __restrict__ rowptr, const int* __restrict__ col,
                              const float* __restrict__ bg, float* __restrict__ h4, int n) {
    int w = threadIdx.x >> 6, lane = threadIdx.x & 63;
    int dst = blockIdx.x * 4 + w;
    if (dst >= n) return;
    int start = rowptr[dst], end = rowptr[dst + 1];
    int eg = lane >> 3;
    int cl = lane & 7;
    float4 acc = make_float4(0.f, 0.f, 0.f, 0.f);
    for (int ib = start; ib < end; ib += 8) {
        int i = ib + eg;
        float nrm = 0.f;
        int s = 0;
        if (i < end) {
            s = col[i];
            nrm = ewg[i];
        }
        float4 hv = ((const float4*)(h3 + (size_t)s * 32))[cl];
        acc.x += hv.x * nrm; acc.y += hv.y * nrm;
        acc.z += hv.z * nrm; acc.w += hv.w * nrm;
    }
#pragma unroll
    for (int off = 8; off <= 32; off <<= 1) {
        acc.x += __shfl_xor(acc.x, off);
        acc.y += __shfl_xor(acc.y, off);
        acc.z += __shfl_xor(acc.z, off);
        acc.w += __shfl_xor(acc.w, off);
    }
    if (lane < 8) {
        float4 bb = ((const float4*)bg)[cl];
        float4 o;
        o.x = fmaxf(acc.x + bb.x, 0.f);
        o.y = fmaxf(acc.y + bb.y, 0.f);
        o.z = fmaxf(acc.z + bb.z, 0.f);
        o.w = fmaxf(acc.w + bb.w, 0.f);
        ((float4*)(h4 + (size_t)dst * 32))[cl] = o;
    }
}

// ---------------- pooling: block-private LDS partials, sparse flush ------------
__global__ void pool_kernel(const float* __restrict__ h4, const int* __restrict__ batch,
                            float* pooled, float* counts, int n) {
    __shared__ float part[64 * 32];
    __shared__ float pcnt[64];
    int t = threadIdx.x;
    for (int i = t; i < 64 * 32; i += 256) part[i] = 0.f;
    if (t < 64) pcnt[t] = 0.f;
    __syncthreads();
    int chunk = (n + gridDim.x - 1) / gridDim.x;
    int begin = blockIdx.x * chunk;
    int end = begin + chunk; if (end > n) end = n;
    int c = t & 31, r = t >> 5;
    for (int node = begin + r; node < end; node += 8) {
        int g = batch[node];
        atomicAdd(&part[g * 32 + c], h4[(size_t)node * 32 + c]);
        if (c == 0) atomicAdd(&pcnt[g], 1.0f);
    }
    __syncthreads();
    for (int i = t; i < 64 * 32; i += 256) {
        float v = part[i];
        if (v != 0.f) atomicAdd(&pooled[i], v);
    }
    if (t < 64) {
        float v = pcnt[t];
        if (v != 0.f) atomicAdd(&counts[t], v);
    }
}

// ---------------- head: pooled -> anomaly[64] + emb[64,64] ----------------
__global__ void head_kernel(const float* __restrict__ pooled_s, const float* __restrict__ counts,
                            const float* __restrict__ A1, const float* __restrict__ ba1,
                            const float* __restrict__ A2, const float* __restrict__ ba2,
                            const float* __restrict__ A3, const float* __restrict__ ba3,
                            const float* __restrict__ Wemb, const float* __restrict__ bemb,
                            float* __restrict__ out) {
    __shared__ float P[64 * 32];
    __shared__ float Z1[64 * 32];
    __shared__ float Z2[64 * 16];
    int t = threadIdx.x;
    for (int i = t; i < 64 * 32; i += 256) {
        int g = i >> 5;
        P[i] = pooled_s[i] / fmaxf(counts[g], 1.0f);
    }
    __syncthreads();
    for (int i = t; i < 64 * 32; i += 256) {
        int g = i >> 5, c = i & 31;
        float a = ba1[c];
#pragma unroll
        for (int k = 0; k < 32; k++) a += P[g * 32 + k] * A1[k * 32 + c];
        Z1[i] = a > 0.f ? a : 0.f;
    }
    __syncthreads();
    for (int i = t; i < 64 * 16; i += 256) {
        int g = i >> 4, c = i & 15;
        float a = ba2[c];
#pragma unroll
        for (int k = 0; k < 32; k++) a += Z1[g * 32 + k] * A2[k * 16 + c];
        Z2[i] = a > 0.f ? a : 0.f;
    }
    __syncthreads();
    for (int g = t; g < 64; g += 256) {
        float a = ba3[0];
#pragma unroll
        for (int k = 0; k < 16; k++) a += Z2[g * 16 + k] * A3[k];
        out[g] = 1.0f / (1.0f + expf(-a));
    }
    for (int i = t; i < 64 * 64; i += 256) {
        int g = i >> 6, c = i & 63;
        float a = bemb[c];
#pragma unroll
        for (int k = 0; k < 32; k++) a += P[g * 32 + k] * Wemb[k * 64 + c];
        out[64 + i] = tanhf(a);
    }
}

extern "C" void kernel_launch(void* const* d_in, const int* in_sizes, int n_in,
                              void* d_out, int out_size, void* d_ws, size_t ws_size,
                              hipStream_t stream) {
    const float* x    = (const float*)d_in[0];
    const int*   ei   = (const int*)d_in[1];
    const int*   batch= (const int*)d_in[2];
    const float* W1   = (const float*)d_in[3];
    const float* as1  = (const float*)d_in[4];
    const float* ad1  = (const float*)d_in[5];
    const float* b1   = (const float*)d_in[6];
    const float* W2   = (const float*)d_in[7];
    const float* as2  = (const float*)d_in[8];
    const float* ad2  = (const float*)d_in[9];
    const float* b2   = (const float*)d_in[10];
    const float* Wg   = (const float*)d_in[11];
    const float* bg   = (const float*)d_in[12];
    const float* A1   = (const float*)d_in[13];
    const float* ba1  = (const float*)d_in[14];
    const float* A2   = (const float*)d_in[15];
    const float* ba2  = (const float*)d_in[16];
    const float* A3   = (const float*)d_in[17];
    const float* ba3  = (const float*)d_in[18];
    const float* Wemb = (const float*)d_in[19];
    const float* bemb = (const float*)d_in[20];
    float* out = (float*)d_out;

    const int N = in_sizes[0] / 32;
    const int E = in_sizes[1] / 2;
    const int ET = E + N;

    char* base = (char*)d_ws;
    size_t off = 0;
    auto take = [&](size_t bytes) -> char* {
        char* p = base + off;
        off = (off + bytes + 255) & ~(size_t)255;
        return p;
    };
    int*   deg    = (int*)take((size_t)N * 4);
    int*   rowptr = (int*)take((size_t)(N + 1) * 4);
    int*   cursor = (int*)take((size_t)N * 4);
    int*   col    = (int*)take((size_t)ET * 4);
    int*   edst   = (int*)take((size_t)ET * 4);
    float* ewbuf  = (float*)take((size_t)ET * 16);   // ew4; later ew2+ewg
    float* dinv   = (float*)take((size_t)N * 4);
    float* als1   = (float*)take((size_t)N * 16);
    float* ald1   = (float*)take((size_t)N * 16);
    int*   bsum   = (int*)take(256 * 4);
    int*   boff   = (int*)take(256 * 4);
    char*  big1   = take((size_t)N * 512);       // h1b bf16; later h2b/h2f/als2/ald2
    char*  big2   = take((size_t)N * 1024);      // out1 fp32; later h3/h4
    float* pooled = (float*)take(64 * 32 * 4);
    float* counts = (float*)take(64 * 4);

    float* ew4 = ewbuf;
    // after gat1_aggregate, ewbuf is reused:
    float* ew2 = ewbuf;
    float* ewg = ewbuf + (size_t)ET;

    __hip_bfloat16* h1b = (__hip_bfloat16*)big1;
    float* out1 = (float*)big2;
    __hip_bfloat16* h2b = (__hip_bfloat16*)big1;
    float* h2f  = (float*)(big1 + (size_t)N * 128);
    float* als2 = (float*)(big1 + (size_t)N * 384);
    float* ald2 = (float*)(big1 + (size_t)N * 388);
    float* h3   = (float*)big2;
    float* h4   = (float*)(big2 + (size_t)N * 128);

    int gN = (N + 255) / 256;
    int gE = (ET + 255) / 256;
    int gN4 = (N + 3) / 4;
    int gN16 = (N + 15) / 16;

    zero_init<<<gN, 256, 0, stream>>>(deg, pooled, counts, N);
    count_edges<<<gE, 256, 0, stream>>>(ei, E, N, deg);
    deg_dinv_bsum<<<gN, 256, 0, stream>>>(deg, dinv, bsum, N);
    scan_bsum<<<1, 256, 0, stream>>>(bsum, boff, rowptr, gN, N);
    write_rowptr<<<gN, 256, 0, stream>>>(deg, boff, rowptr, cursor, N);

    gat1_transform<<<gN16, 256, 0, stream>>>(x, W1, as1, ad1, h1b, als1, ald1, N);
    fill_edges<<<gE, 256, 0, stream>>>(ei, E, N, cursor, col, edst, ew4, als1, ald1);
    gat1_aggregate<<<N, 256, 0, stream>>>((const unsigned short*)h1b, ew4,
                                          rowptr, col, b1, out1, N);

    gat2_transform<<<gN16, 256, 0, stream>>>(out1, W2, as2, ad2, h2b, als2, ald2, N);
    edge_w2<<<gE, 256, 0, stream>>>(col, edst, als2, ald2, dinv, ew2, ewg, ET);
    gat2_aggregate<<<gN4, 256, 0, stream>>>((const unsigned short*)h2b, ew2,
                                            rowptr, col, b2, h2f, N);

    gcn_transform<<<(N * 32 + 255) / 256, 256, 0, stream>>>(h2f, Wg, h3, N);
    gcn_aggregate<<<gN4, 256, 0, stream>>>(h3, ewg, rowptr, col, bg, h4, N);
    pool_kernel<<<256, 256, 0, stream>>>(h4, batch, pooled, counts, N);

    head_kernel<<<1, 256, 0, stream>>>(pooled, counts, A1, ba1, A2, ba2, A3, ba3,
                                       Wemb, bemb, out);
}

// Round 13
// 269.890 us; speedup vs baseline: 1.1248x; 1.0781x over previous
//
#include <hip/hip_runtime.h>
#include <hip/hip_bf16.h>

#define NEG 0.2f

typedef short bf16x8 __attribute__((ext_vector_type(8)));
typedef float floatx4 __attribute__((ext_vector_type(4)));

__device__ __forceinline__ float leaky(float v) { return v > 0.f ? v : NEG * v; }

__device__ __forceinline__ void unpack2(unsigned w, float& lo, float& hi) {
    union { unsigned u; float f; } a, b;
    a.u = w << 16;
    b.u = w & 0xffff0000u;
    lo = a.f; hi = b.f;
}

__device__ __forceinline__ unsigned short f2bf(float f) {
    union { float f; unsigned u; } v; v.f = f;
    unsigned r = v.u + 0x7fff + ((v.u >> 16) & 1);   // round-nearest-even
    return (unsigned short)(r >> 16);
}

// ---------------- init ----------------
__global__ void zero_init(int* deg, float* pooled, float* counts, int n) {
    int i = blockIdx.x * blockDim.x + threadIdx.x;
    if (i < n) deg[i] = 0;
    if (i < 64 * 32) pooled[i] = 0.f;
    if (i < 64) counts[i] = 0.f;
}

// ---------------- CSR build ----------------
__global__ void count_edges(const int* __restrict__ ei, int E, int n, int* deg) {
    int i = blockIdx.x * blockDim.x + threadIdx.x;
    int tot = E + n;
    if (i < tot) {
        int dst = (i < E) ? ei[E + i] : (i - E);
        atomicAdd(&deg[dst], 1);
    }
}

__global__ void deg_dinv_bsum(const int* __restrict__ deg, float* __restrict__ dinv,
                              int* __restrict__ bsum, int n) {
    __shared__ int red[256];
    int t = threadIdx.x;
    int i = blockIdx.x * 256 + t;
    int d = (i < n) ? deg[i] : 0;
    if (i < n) dinv[i] = rsqrtf(fmaxf((float)d, 1.0f));
    red[t] = d;
    __syncthreads();
    for (int off = 128; off; off >>= 1) {
        if (t < off) red[t] += red[t + off];
        __syncthreads();
    }
    if (t == 0) bsum[blockIdx.x] = red[0];
}

__global__ void scan_bsum(const int* __restrict__ bsum, int* __restrict__ boff,
                          int* __restrict__ rowptr, int nb, int n) {
    __shared__ int s[256];
    int t = threadIdx.x;
    int own = (t < nb) ? bsum[t] : 0;
    s[t] = own;
    __syncthreads();
    for (int off = 1; off < 256; off <<= 1) {
        int v = (t >= off) ? s[t - off] : 0;
        __syncthreads();
        s[t] += v;
        __syncthreads();
    }
    if (t < nb) boff[t] = s[t] - own;
    if (t == 255) rowptr[n] = s[255];
}

__global__ void write_rowptr(const int* __restrict__ deg, const int* __restrict__ boff,
                             int* __restrict__ rowptr, int* __restrict__ cursor, int n) {
    __shared__ int s[256];
    int t = threadIdx.x;
    int i = blockIdx.x * 256 + t;
    int d = (i < n) ? deg[i] : 0;
    s[t] = d;
    __syncthreads();
    for (int off = 1; off < 256; off <<= 1) {
        int v = (t >= off) ? s[t - off] : 0;
        __syncthreads();
        s[t] += v;
        __syncthreads();
    }
    if (i < n) {
        int r = boff[blockIdx.x] + s[t] - d;
        rowptr[i] = r;
        cursor[i] = r;
    }
}

// runs AFTER gat1_transform: precomputes per-edge GAT1 weights (4 heads) + edst
__global__ void fill_edges(const int* __restrict__ ei, int E, int n, int* cursor,
                           int* __restrict__ col, int* __restrict__ edst,
                           float* __restrict__ ew4,
                           const float* __restrict__ als1, const float* __restrict__ ald1) {
    int i = blockIdx.x * blockDim.x + threadIdx.x;
    int tot = E + n;
    if (i < tot) {
        int src, dst;
        if (i < E) { src = ei[i]; dst = ei[E + i]; }
        else { src = i - E; dst = i - E; }
        int pos = atomicAdd(&cursor[dst], 1);
        col[pos] = src;
        edst[pos] = dst;
        float4 as = ((const float4*)als1)[src];
        float4 ad = ((const float4*)ald1)[dst];
        float4 w;
        w.x = __expf(leaky(as.x + ad.x));
        w.y = __expf(leaky(as.y + ad.y));
        w.z = __expf(leaky(as.z + ad.z));
        w.w = __expf(leaky(as.w + ad.w));
        ((float4*)ew4)[pos] = w;
    }
}

// after gat2_mfma: per-edge GAT2 weight + fused GCN norm
__global__ void edge_w2(const int* __restrict__ col, const int* __restrict__ edst,
                        const float* __restrict__ als2, const float* __restrict__ ald2,
                        const float* __restrict__ dinv,
                        float* __restrict__ ew2, float* __restrict__ ewg, int et) {
    int i = blockIdx.x * blockDim.x + threadIdx.x;
    if (i < et) {
        int s = col[i], d = edst[i];
        ew2[i] = __expf(leaky(als2[s] + ald2[d]));
        ewg[i] = dinv[s] * dinv[d];
    }
}

// ---------------- GAT1: x[N,32] @ W1[32,256]; h1 stored bf16 ----
__global__ void gat1_transform(const float* __restrict__ x, const float* __restrict__ W1,
                               const float* __restrict__ asr, const float* __restrict__ adt,
                               __hip_bfloat16* __restrict__ h1b, float* __restrict__ als,
                               float* __restrict__ ald, int n) {
    __shared__ float xr[16][32];
    int t = threadIdx.x;  // 256
    int base = blockIdx.x * 16;
    float w1r[32];
#pragma unroll
    for (int j = 0; j < 32; j++) w1r[j] = W1[j * 256 + t];
    if (t < 128) {
        int node = t >> 3;
        float4 v = make_float4(0.f, 0.f, 0.f, 0.f);
        if (base + node < n) v = ((const float4*)(x + (size_t)base * 32))[t];
        ((float4*)&xr[0][0])[t] = v;
    }
    __syncthreads();
    int head = t >> 6, lane = t & 63;
    float a_s = asr[t];
    float a_d = adt[t];
    for (int nn = 0; nn < 16; nn++) {
        int node = base + nn;
        float acc0 = 0.f, acc1 = 0.f, acc2 = 0.f, acc3 = 0.f;
#pragma unroll
        for (int j = 0; j < 32; j += 4) {
            acc0 += xr[nn][j]     * w1r[j];
            acc1 += xr[nn][j + 1] * w1r[j + 1];
            acc2 += xr[nn][j + 2] * w1r[j + 2];
            acc3 += xr[nn][j + 3] * w1r[j + 3];
        }
        float acc = (acc0 + acc1) + (acc2 + acc3);
        if (node < n) h1b[(size_t)node * 256 + t] = __float2bfloat16(acc);
        float ps = acc * a_s;
        float pd = acc * a_d;
#pragma unroll
        for (int off = 32; off; off >>= 1) {
            ps += __shfl_down(ps, off);
            pd += __shfl_down(pd, off);
        }
        if (node < n && lane == 0) { als[node * 4 + head] = ps; ald[node * 4 + head] = pd; }
    }
}

// one block per dst; wave w = head; 8 edges x 8 lanes x 16B bf16.
// Weights precomputed in ew4. Output written as bf16 (feeds MFMA gat2).
__global__ void gat1_aggregate(const unsigned short* __restrict__ h1b,
                               const float* __restrict__ ew4,
                               const int* __restrict__ rowptr,
                               const int* __restrict__ col, const float* __restrict__ b1,
                               unsigned short* __restrict__ out1b, int n) {
    int dst = blockIdx.x;
    int head = threadIdx.x >> 6, lane = threadIdx.x & 63;
    int start = rowptr[dst], end = rowptr[dst + 1];

    int eg = lane >> 3;
    int cl = lane & 7;
    float acc[8];
#pragma unroll
    for (int j = 0; j < 8; j++) acc[j] = 0.f;
    float wsum = 0.f;
    for (int ib = start; ib < end; ib += 8) {
        int i = ib + eg;
        float w = 0.f;
        int s = 0;
        if (i < end) {
            s = col[i];
            w = ew4[i * 4 + head];
        }
        wsum += w;
        uint4 hv = *((const uint4*)(h1b + (size_t)s * 256 + head * 64) + cl);
        float l0, u0, l1, u1, l2, u2, l3, u3;
        unpack2(hv.x, l0, u0); unpack2(hv.y, l1, u1);
        unpack2(hv.z, l2, u2); unpack2(hv.w, l3, u3);
        acc[0] += l0 * w; acc[1] += u0 * w;
        acc[2] += l1 * w; acc[3] += u1 * w;
        acc[4] += l2 * w; acc[5] += u2 * w;
        acc[6] += l3 * w; acc[7] += u3 * w;
    }
#pragma unroll
    for (int off = 8; off <= 32; off <<= 1) {
        wsum += __shfl_xor(wsum, off);
#pragma unroll
        for (int j = 0; j < 8; j++) acc[j] += __shfl_xor(acc[j], off);
    }
    float inv = 1.0f / (wsum + 1e-16f);
    if (lane < 8) {
        const float* bb = b1 + head * 64 + cl * 8;
        unsigned short pk[8];
#pragma unroll
        for (int j = 0; j < 8; j++) pk[j] = f2bf(fmaxf(acc[j] * inv + bb[j], 0.f));
        *((uint4*)(out1b + (size_t)dst * 256 + head * 64 + cl * 8)) = *(const uint4*)pk;
    }
}

// ---------------- pack W2 into MFMA B-fragment layout (bf16) ----------------
// fragment (ct, kt): lane holds B[k = kt*32 + (lane>>4)*8 + j][n = ct*16 + (lane&15)]
__global__ void pack_w2(const float* __restrict__ W2, unsigned short* __restrict__ W2p) {
    int t = threadIdx.x;
    for (int idx = t; idx < 32 * 64; idx += 256) {
        int frag = idx >> 6, lane = idx & 63;
        int ct = frag >> 3, kt = frag & 7;
        int nn = ct * 16 + (lane & 15);
        int kb = kt * 32 + (lane >> 4) * 8;
#pragma unroll
        for (int j = 0; j < 8; j++)
            W2p[frag * 512 + lane * 8 + j] = f2bf(W2[(kb + j) * 64 + nn]);
    }
}

// ---------------- GAT2 transform via MFMA 16x16x32 bf16 ----------------
// 16 nodes/block; wave w = col-tile w (cols w*16..w*16+15); 8 K-steps.
// A: out1b rows staged in LDS (row stride 264 bf16 to break bank conflicts).
// Epilogue: h2b + attention logits als2/ald2 (shuffle + LDS cross-wave reduce).
__global__ void gat2_mfma(const unsigned short* __restrict__ out1b,
                          const unsigned short* __restrict__ W2p,
                          const float* __restrict__ asr, const float* __restrict__ adt,
                          __hip_bfloat16* __restrict__ h2b, float* __restrict__ als,
                          float* __restrict__ ald, int n) {
    __shared__ unsigned short xs[16 * 264];
    __shared__ float aps[4][16];
    __shared__ float apd[4][16];
    int t = threadIdx.x;
    int w = t >> 6, lane = t & 63;
    int base = blockIdx.x * 16;
    // stage 16 node rows (256 bf16 each) -> LDS, padded stride 264
    for (int i = t; i < 512; i += 256) {
        int nn = i >> 5, c = i & 31;
        uint4 v = make_uint4(0u, 0u, 0u, 0u);
        if (base + nn < n) v = *((const uint4*)(out1b + (size_t)(base + nn) * 256 + c * 8));
        *((uint4*)(xs + nn * 264 + c * 8)) = v;
    }
    __syncthreads();

    int m = lane & 15, quad = lane >> 4;
    floatx4 acc = {0.f, 0.f, 0.f, 0.f};
#pragma unroll
    for (int kt = 0; kt < 8; kt++) {
        bf16x8 a = *((const bf16x8*)(xs + m * 264 + kt * 32 + quad * 8));
        bf16x8 b = *((const bf16x8*)(W2p + (w * 8 + kt) * 512 + lane * 8));
        acc = __builtin_amdgcn_mfma_f32_16x16x32_bf16(a, b, acc, 0, 0, 0);
    }
    // C/D: col = ct*16 + (lane&15), row = quad*4 + q
    int colg = w * 16 + m;
    float a_s = asr[colg], a_d = adt[colg];
    float ps[4], pd[4];
#pragma unroll
    for (int q = 0; q < 4; q++) {
        int node = base + quad * 4 + q;
        if (node < n) h2b[(size_t)node * 64 + colg] = __float2bfloat16(acc[q]);
        ps[q] = acc[q] * a_s;
        pd[q] = acc[q] * a_d;
#pragma unroll
        for (int off = 1; off <= 8; off <<= 1) {
            ps[q] += __shfl_xor(ps[q], off);
            pd[q] += __shfl_xor(pd[q], off);
        }
        if (m == 0) {
            aps[w][quad * 4 + q] = ps[q];
            apd[w][quad * 4 + q] = pd[q];
        }
    }
    __syncthreads();
    if (t < 16 && base + t < n) {
        als[base + t] = aps[0][t] + aps[1][t] + aps[2][t] + aps[3][t];
        ald[base + t] = apd[0][t] + apd[1][t] + apd[2][t] + apd[3][t];
    }
}

// wave per dst; weights precomputed in ew2
__global__ void gat2_aggregate(const unsigned short* __restrict__ h2b,
                               const float* __restrict__ ew2,
                               const int* __restrict__ rowptr,
                               const int* __restrict__ col, const float* __restrict__ b2,
                               float* __restrict__ h2f, int n) {
    int w = threadIdx.x >> 6, lane = threadIdx.x & 63;
    int dst = blockIdx.x * 4 + w;
    if (dst >= n) return;
    int start = rowptr[dst], end = rowptr[dst + 1];

    int eg = lane >> 3;
    int cl = lane & 7;
    float acc[8];
#pragma unroll
    for (int j = 0; j < 8; j++) acc[j] = 0.f;
    float wsum = 0.f;
    for (int ib = start; ib < end; ib += 8) {
        int i = ib + eg;
        float wv = 0.f;
        int s = 0;
        if (i < end) {
            s = col[i];
            wv = ew2[i];
        }
        wsum += wv;
        uint4 hv = *((const uint4*)(h2b + (size_t)s * 64) + cl);
        float l0, u0, l1, u1, l2, u2, l3, u3;
        unpack2(hv.x, l0, u0); unpack2(hv.y, l1, u1);
        unpack2(hv.z, l2, u2); unpack2(hv.w, l3, u3);
        acc[0] += l0 * wv; acc[1] += u0 * wv;
        acc[2] += l1 * wv; acc[3] += u1 * wv;
        acc[4] += l2 * wv; acc[5] += u2 * wv;
        acc[6] += l3 * wv; acc[7] += u3 * wv;
    }
#pragma unroll
    for (int off = 8; off <= 32; off <<= 1) {
        wsum += __shfl_xor(wsum, off);
#pragma unroll
        for (int j = 0; j < 8; j++) acc[j] += __shfl_xor(acc[j], off);
    }
    float inv = 1.0f / (wsum + 1e-16f);
    if (lane < 8) {
        float4 o0, o1;
        const float* bb = b2 + cl * 8;
        o0.x = fmaxf(acc[0] * inv + bb[0], 0.f);
        o0.y = fmaxf(acc[1] * inv + bb[1], 0.f);
        o0.z = fmaxf(acc[2] * inv + bb[2], 0.f);
        o0.w = fmaxf(acc[3] * inv + bb[3], 0.f);
        o1.x = fmaxf(acc[4] * inv + bb[4], 0.f);
        o1.y = fmaxf(acc[5] * inv + bb[5], 0.f);
        o1.z = fmaxf(acc[6] * inv + bb[6], 0.f);
        o1.w = fmaxf(acc[7] * inv + bb[7], 0.f);
        float4* op = (float4*)(h2f + (size_t)dst * 64 + cl * 8);
        op[0] = o0; op[1] = o1;
    }
}

// ---------------- GCN: h2f[N,64] @ Wg[64,32] ----------------
__global__ void gcn_transform(const float* __restrict__ h2f, const float* __restrict__ Wg,
                              float* __restrict__ h3, int n) {
    int idx = blockIdx.x * blockDim.x + threadIdx.x;
    if (idx >= n * 32) return;
    int node = idx >> 5, c = idx & 31;
    float acc = 0.f;
#pragma unroll 8
    for (int k = 0; k < 64; k++) acc += h2f[node * 64 + k] * Wg[k * 32 + c];
    h3[idx] = acc;
}

// wave per dst; full edge norm precomputed in ewg (dinv[s]*dinv[d])
__global__ void gcn_aggregate(const float* __restrict__ h3, const float* __restrict__ ewg,
                              const int* __restrict__ rowptr, const int* __restrict__ col,
                              const float* __restrict__ bg, float* __restrict__ h4, int n) {
    int w = threadIdx.x >> 6, lane = threadIdx.x & 63;
    int dst = blockIdx.x * 4 + w;
    if (dst >= n) return;
    int start = rowptr[dst], end = rowptr[dst + 1];
    int eg = lane >> 3;
    int cl = lane & 7;
    float4 acc = make_float4(0.f, 0.f, 0.f, 0.f);
    for (int ib = start; ib < end; ib += 8) {
        int i = ib + eg;
        float nrm = 0.f;
        int s = 0;
        if (i < end) {
            s = col[i];
            nrm = ewg[i];
        }
        float4 hv = ((const float4*)(h3 + (size_t)s * 32))[cl];
        acc.x += hv.x * nrm; acc.y += hv.y * nrm;
        acc.z += hv.z * nrm; acc.w += hv.w * nrm;
    }
#pragma unroll
    for (int off = 8; off <= 32; off <<= 1) {
        acc.x += __shfl_xor(acc.x, off);
        acc.y += __shfl_xor(acc.y, off);
        acc.z += __shfl_xor(acc.z, off);
        acc.w += __shfl_xor(acc.w, off);
    }
    if (lane < 8) {
        float4 bb = ((const float4*)bg)[cl];
        float4 o;
        o.x = fmaxf(acc.x + bb.x, 0.f);
        o.y = fmaxf(acc.y + bb.y, 0.f);
        o.z = fmaxf(acc.z + bb.z, 0.f);
        o.w = fmaxf(acc.w + bb.w, 0.f);
        ((float4*)(h4 + (size_t)dst * 32))[cl] = o;
    }
}

// ---------------- pooling: block-private LDS partials, sparse flush ------------
__global__ void pool_kernel(const float* __restrict__ h4, const int* __restrict__ batch,
                            float* pooled, float* counts, int n) {
    __shared__ float part[64 * 32];
    __shared__ float pcnt[64];
    int t = threadIdx.x;
    for (int i = t; i < 64 * 32; i += 256) part[i] = 0.f;
    if (t < 64) pcnt[t] = 0.f;
    __syncthreads();
    int chunk = (n + gridDim.x - 1) / gridDim.x;
    int begin = blockIdx.x * chunk;
    int end = begin + chunk; if (end > n) end = n;
    int c = t & 31, r = t >> 5;
    for (int node = begin + r; node < end; node += 8) {
        int g = batch[node];
        atomicAdd(&part[g * 32 + c], h4[(size_t)node * 32 + c]);
        if (c == 0) atomicAdd(&pcnt[g], 1.0f);
    }
    __syncthreads();
    for (int i = t; i < 64 * 32; i += 256) {
        float v = part[i];
        if (v != 0.f) atomicAdd(&pooled[i], v);
    }
    if (t < 64) {
        float v = pcnt[t];
        if (v != 0.f) atomicAdd(&counts[t], v);
    }
}

// ---------------- head: pooled -> anomaly[64] + emb[64,64] ----------------
__global__ void head_kernel(const float* __restrict__ pooled_s, const float* __restrict__ counts,
                            const float* __restrict__ A1, const float* __restrict__ ba1,
                            const float* __restrict__ A2, const float* __restrict__ ba2,
                            const float* __restrict__ A3, const float* __restrict__ ba3,
                            const float* __restrict__ Wemb, const float* __restrict__ bemb,
                            float* __restrict__ out) {
    __shared__ float P[64 * 32];
    __shared__ float Z1[64 * 32];
    __shared__ float Z2[64 * 16];
    int t = threadIdx.x;
    for (int i = t; i < 64 * 32; i += 256) {
        int g = i >> 5;
        P[i] = pooled_s[i] / fmaxf(counts[g], 1.0f);
    }
    __syncthreads();
    for (int i = t; i < 64 * 32; i += 256) {
        int g = i >> 5, c = i & 31;
        float a = ba1[c];
#pragma unroll
        for (int k = 0; k < 32; k++) a += P[g * 32 + k] * A1[k * 32 + c];
        Z1[i] = a > 0.f ? a : 0.f;
    }
    __syncthreads();
    for (int i = t; i < 64 * 16; i += 256) {
        int g = i >> 4, c = i & 15;
        float a = ba2[c];
#pragma unroll
        for (int k = 0; k < 32; k++) a += Z1[g * 32 + k] * A2[k * 16 + c];
        Z2[i] = a > 0.f ? a : 0.f;
    }
    __syncthreads();
    for (int g = t; g < 64; g += 256) {
        float a = ba3[0];
#pragma unroll
        for (int k = 0; k < 16; k++) a += Z2[g * 16 + k] * A3[k];
        out[g] = 1.0f / (1.0f + expf(-a));
    }
    for (int i = t; i < 64 * 64; i += 256) {
        int g = i >> 6, c = i & 63;
        float a = bemb[c];
#pragma unroll
        for (int k = 0; k < 32; k++) a += P[g * 32 + k] * Wemb[k * 64 + c];
        out[64 + i] = tanhf(a);
    }
}

extern "C" void kernel_launch(void* const* d_in, const int* in_sizes, int n_in,
                              void* d_out, int out_size, void* d_ws, size_t ws_size,
                              hipStream_t stream) {
    const float* x    = (const float*)d_in[0];
    const int*   ei   = (const int*)d_in[1];
    const int*   batch= (const int*)d_in[2];
    const float* W1   = (const float*)d_in[3];
    const float* as1  = (const float*)d_in[4];
    const float* ad1  = (const float*)d_in[5];
    const float* b1   = (const float*)d_in[6];
    const float* W2   = (const float*)d_in[7];
    const float* as2  = (const float*)d_in[8];
    const float* ad2  = (const float*)d_in[9];
    const float* b2   = (const float*)d_in[10];
    const float* Wg   = (const float*)d_in[11];
    const float* bg   = (const float*)d_in[12];
    const float* A1   = (const float*)d_in[13];
    const float* ba1  = (const float*)d_in[14];
    const float* A2   = (const float*)d_in[15];
    const float* ba2  = (const float*)d_in[16];
    const float* A3   = (const float*)d_in[17];
    const float* ba3  = (const float*)d_in[18];
    const float* Wemb = (const float*)d_in[19];
    const float* bemb = (const float*)d_in[20];
    float* out = (float*)d_out;

    const int N = in_sizes[0] / 32;
    const int E = in_sizes[1] / 2;
    const int ET = E + N;

    char* base = (char*)d_ws;
    size_t off = 0;
    auto take = [&](size_t bytes) -> char* {
        char* p = base + off;
        off = (off + bytes + 255) & ~(size_t)255;
        return p;
    };
    int*   deg    = (int*)take((size_t)N * 4);
    int*   rowptr = (int*)take((size_t)(N + 1) * 4);
    int*   cursor = (int*)take((size_t)N * 4);
    int*   col    = (int*)take((size_t)ET * 4);
    int*   edst   = (int*)take((size_t)ET * 4);
    float* ewbuf  = (float*)take((size_t)ET * 16);   // ew4; later ew2+ewg
    float* dinv   = (float*)take((size_t)N * 4);
    float* als1   = (float*)take((size_t)N * 16);
    float* ald1   = (float*)take((size_t)N * 16);
    int*   bsum   = (int*)take(256 * 4);
    int*   boff   = (int*)take(256 * 4);
    unsigned short* W2p = (unsigned short*)take(32 * 512 * 2);   // packed B-frags
    char*  big1   = take((size_t)N * 512);       // h1b bf16; later h2b/h2f/als2/ald2
    char*  big2   = take((size_t)N * 1024);      // out1b bf16 + h3/h4
    float* pooled = (float*)take(64 * 32 * 4);
    float* counts = (float*)take(64 * 4);

    float* ew4 = ewbuf;
    float* ew2 = ewbuf;                      // reuse after gat1_aggregate
    float* ewg = ewbuf + (size_t)ET;

    __hip_bfloat16* h1b = (__hip_bfloat16*)big1;
    __hip_bfloat16* h2b = (__hip_bfloat16*)big1;                  // after h1b dead
    float* h2f  = (float*)(big1 + (size_t)N * 128);
    float* als2 = (float*)(big1 + (size_t)N * 384);
    float* ald2 = (float*)(big1 + (size_t)N * 388);
    unsigned short* out1b = (unsigned short*)big2;                // N*512 B
    float* h3   = (float*)(big2 + (size_t)N * 512);               // N*128 B
    float* h4   = (float*)(big2 + (size_t)N * 640);               // N*128 B

    int gN = (N + 255) / 256;
    int gE = (ET + 255) / 256;
    int gN4 = (N + 3) / 4;
    int gN16 = (N + 15) / 16;

    zero_init<<<gN, 256, 0, stream>>>(deg, pooled, counts, N);
    count_edges<<<gE, 256, 0, stream>>>(ei, E, N, deg);
    deg_dinv_bsum<<<gN, 256, 0, stream>>>(deg, dinv, bsum, N);
    scan_bsum<<<1, 256, 0, stream>>>(bsum, boff, rowptr, gN, N);
    write_rowptr<<<gN, 256, 0, stream>>>(deg, boff, rowptr, cursor, N);
    pack_w2<<<1, 256, 0, stream>>>(W2, W2p);

    gat1_transform<<<gN16, 256, 0, stream>>>(x, W1, as1, ad1, h1b, als1, ald1, N);
    fill_edges<<<gE, 256, 0, stream>>>(ei, E, N, cursor, col, edst, ew4, als1, ald1);
    gat1_aggregate<<<N, 256, 0, stream>>>((const unsigned short*)h1b, ew4,
                                          rowptr, col, b1, out1b, N);

    gat2_mfma<<<gN16, 256, 0, stream>>>(out1b, W2p, as2, ad2, h2b, als2, ald2, N);
    edge_w2<<<gE, 256, 0, stream>>>(col, edst, als2, ald2, dinv, ew2, ewg, ET);
    gat2_aggregate<<<gN4, 256, 0, stream>>>((const unsigned short*)h2b, ew2,
                                            rowptr, col, b2, h2f, N);

    gcn_transform<<<(N * 32 + 255) / 256, 256, 0, stream>>>(h2f, Wg, h3, N);
    gcn_aggregate<<<gN4, 256, 0, stream>>>(h3, ewg, rowptr, col, bg, h4, N);
    pool_kernel<<<256, 256, 0, stream>>>(h4, batch, pooled, counts, N);

    head_kernel<<<1, 256, 0, stream>>>(pooled, counts, A1, ba1, A2, ba2, A3, ba3,
                                       Wemb, bemb, out);
}

// Round 14
// 264.242 us; speedup vs baseline: 1.1489x; 1.0214x over previous
//
#include <hip/hip_runtime.h>
#include <hip/hip_bf16.h>

#define NEG 0.2f

typedef short bf16x8 __attribute__((ext_vector_type(8)));
typedef float floatx4 __attribute__((ext_vector_type(4)));

__device__ __forceinline__ float leaky(float v) { return v > 0.f ? v : NEG * v; }

__device__ __forceinline__ void unpack2(unsigned w, float& lo, float& hi) {
    union { unsigned u; float f; } a, b;
    a.u = w << 16;
    b.u = w & 0xffff0000u;
    lo = a.f; hi = b.f;
}

__device__ __forceinline__ unsigned short f2bf(float f) {
    union { float f; unsigned u; } v; v.f = f;
    unsigned r = v.u + 0x7fff + ((v.u >> 16) & 1);   // round-nearest-even
    return (unsigned short)(r >> 16);
}

// ---------------- init ----------------
__global__ void zero_init(int* deg, float* pooled, float* counts, int n) {
    int i = blockIdx.x * blockDim.x + threadIdx.x;
    if (i < n) deg[i] = 0;
    if (i < 64 * 32) pooled[i] = 0.f;
    if (i < 64) counts[i] = 0.f;
}

// ---------------- CSR build ----------------
__global__ void count_edges(const int* __restrict__ ei, int E, int n, int* deg) {
    int i = blockIdx.x * blockDim.x + threadIdx.x;
    int tot = E + n;
    if (i < tot) {
        int dst = (i < E) ? ei[E + i] : (i - E);
        atomicAdd(&deg[dst], 1);
    }
}

__global__ void deg_dinv_bsum(const int* __restrict__ deg, float* __restrict__ dinv,
                              int* __restrict__ bsum, int n) {
    __shared__ int red[256];
    int t = threadIdx.x;
    int i = blockIdx.x * 256 + t;
    int d = (i < n) ? deg[i] : 0;
    if (i < n) dinv[i] = rsqrtf(fmaxf((float)d, 1.0f));
    red[t] = d;
    __syncthreads();
    for (int off = 128; off; off >>= 1) {
        if (t < off) red[t] += red[t + off];
        __syncthreads();
    }
    if (t == 0) bsum[blockIdx.x] = red[0];
}

__global__ void scan_bsum(const int* __restrict__ bsum, int* __restrict__ boff,
                          int* __restrict__ rowptr, int nb, int n) {
    __shared__ int s[256];
    int t = threadIdx.x;
    int own = (t < nb) ? bsum[t] : 0;
    s[t] = own;
    __syncthreads();
    for (int off = 1; off < 256; off <<= 1) {
        int v = (t >= off) ? s[t - off] : 0;
        __syncthreads();
        s[t] += v;
        __syncthreads();
    }
    if (t < nb) boff[t] = s[t] - own;
    if (t == 255) rowptr[n] = s[255];
}

__global__ void write_rowptr(const int* __restrict__ deg, const int* __restrict__ boff,
                             int* __restrict__ rowptr, int* __restrict__ cursor, int n) {
    __shared__ int s[256];
    int t = threadIdx.x;
    int i = blockIdx.x * 256 + t;
    int d = (i < n) ? deg[i] : 0;
    s[t] = d;
    __syncthreads();
    for (int off = 1; off < 256; off <<= 1) {
        int v = (t >= off) ? s[t - off] : 0;
        __syncthreads();
        s[t] += v;
        __syncthreads();
    }
    if (i < n) {
        int r = boff[blockIdx.x] + s[t] - d;
        rowptr[i] = r;
        cursor[i] = r;
    }
}

// runs AFTER gat1_transform: precomputes per-edge GAT1 weights (4 heads) + edst
__global__ void fill_edges(const int* __restrict__ ei, int E, int n, int* cursor,
                           int* __restrict__ col, int* __restrict__ edst,
                           float* __restrict__ ew4,
                           const float* __restrict__ als1, const float* __restrict__ ald1) {
    int i = blockIdx.x * blockDim.x + threadIdx.x;
    int tot = E + n;
    if (i < tot) {
        int src, dst;
        if (i < E) { src = ei[i]; dst = ei[E + i]; }
        else { src = i - E; dst = i - E; }
        int pos = atomicAdd(&cursor[dst], 1);
        col[pos] = src;
        edst[pos] = dst;
        float4 as = ((const float4*)als1)[src];
        float4 ad = ((const float4*)ald1)[dst];
        float4 w;
        w.x = __expf(leaky(as.x + ad.x));
        w.y = __expf(leaky(as.y + ad.y));
        w.z = __expf(leaky(as.z + ad.z));
        w.w = __expf(leaky(as.w + ad.w));
        ((float4*)ew4)[pos] = w;
    }
}

// after gat2_mfma: per-edge GAT2 weight + fused GCN norm
__global__ void edge_w2(const int* __restrict__ col, const int* __restrict__ edst,
                        const float* __restrict__ als2, const float* __restrict__ ald2,
                        const float* __restrict__ dinv,
                        float* __restrict__ ew2, float* __restrict__ ewg, int et) {
    int i = blockIdx.x * blockDim.x + threadIdx.x;
    if (i < et) {
        int s = col[i], d = edst[i];
        ew2[i] = __expf(leaky(als2[s] + ald2[d]));
        ewg[i] = dinv[s] * dinv[d];
    }
}

// ---------------- GAT1: x[N,32] @ W1[32,256]; h1 stored bf16 ----
__global__ void gat1_transform(const float* __restrict__ x, const float* __restrict__ W1,
                               const float* __restrict__ asr, const float* __restrict__ adt,
                               __hip_bfloat16* __restrict__ h1b, float* __restrict__ als,
                               float* __restrict__ ald, int n) {
    __shared__ float xr[16][32];
    int t = threadIdx.x;  // 256
    int base = blockIdx.x * 16;
    float w1r[32];
#pragma unroll
    for (int j = 0; j < 32; j++) w1r[j] = W1[j * 256 + t];
    if (t < 128) {
        int node = t >> 3;
        float4 v = make_float4(0.f, 0.f, 0.f, 0.f);
        if (base + node < n) v = ((const float4*)(x + (size_t)base * 32))[t];
        ((float4*)&xr[0][0])[t] = v;
    }
    __syncthreads();
    int head = t >> 6, lane = t & 63;
    float a_s = asr[t];
    float a_d = adt[t];
    for (int nn = 0; nn < 16; nn++) {
        int node = base + nn;
        float acc0 = 0.f, acc1 = 0.f, acc2 = 0.f, acc3 = 0.f;
#pragma unroll
        for (int j = 0; j < 32; j += 4) {
            acc0 += xr[nn][j]     * w1r[j];
            acc1 += xr[nn][j + 1] * w1r[j + 1];
            acc2 += xr[nn][j + 2] * w1r[j + 2];
            acc3 += xr[nn][j + 3] * w1r[j + 3];
        }
        float acc = (acc0 + acc1) + (acc2 + acc3);
        if (node < n) h1b[(size_t)node * 256 + t] = __float2bfloat16(acc);
        float ps = acc * a_s;
        float pd = acc * a_d;
#pragma unroll
        for (int off = 32; off; off >>= 1) {
            ps += __shfl_down(ps, off);
            pd += __shfl_down(pd, off);
        }
        if (node < n && lane == 0) { als[node * 4 + head] = ps; ald[node * 4 + head] = pd; }
    }
}

// XCD-aware head partitioning: blocks dispatch round-robin over the 8 XCDs
// (blockIdx % 8 ~ XCD on MI355X; speed heuristic only, G16-safe). A block
// handles ONE head x 4 dsts (wave = dst). head = (blockIdx&7)>>1 pins each
// head's 2.56 MB h1b slice into 2 XCDs' L2 instead of thrashing the full
// 10 MB table across all 8. col/ew4 streams are dst-partitioned -> ~1/8
// per XCD. Weights precomputed in ew4; wsum xor-reduce over eg bits only.
__global__ void gat1_aggregate(const unsigned short* __restrict__ h1b,
                               const float* __restrict__ ew4,
                               const int* __restrict__ rowptr,
                               const int* __restrict__ col, const float* __restrict__ b1,
                               unsigned short* __restrict__ out1b, int n) {
    int head = (blockIdx.x & 7) >> 1;
    int quad = (blockIdx.x >> 3) * 2 + (blockIdx.x & 1);
    int w = threadIdx.x >> 6, lane = threadIdx.x & 63;
    int dst = quad * 4 + w;
    if (dst >= n) return;
    int start = rowptr[dst], end = rowptr[dst + 1];

    int eg = lane >> 3;
    int cl = lane & 7;
    float acc[8];
#pragma unroll
    for (int j = 0; j < 8; j++) acc[j] = 0.f;
    float wsum = 0.f;
    for (int ib = start; ib < end; ib += 8) {
        int i = ib + eg;
        float wv = 0.f;
        int s = 0;
        if (i < end) {
            s = col[i];
            wv = ew4[i * 4 + head];
        }
        wsum += wv;
        uint4 hv = *((const uint4*)(h1b + (size_t)s * 256 + head * 64) + cl);
        float l0, u0, l1, u1, l2, u2, l3, u3;
        unpack2(hv.x, l0, u0); unpack2(hv.y, l1, u1);
        unpack2(hv.z, l2, u2); unpack2(hv.w, l3, u3);
        acc[0] += l0 * wv; acc[1] += u0 * wv;
        acc[2] += l1 * wv; acc[3] += u1 * wv;
        acc[4] += l2 * wv; acc[5] += u2 * wv;
        acc[6] += l3 * wv; acc[7] += u3 * wv;
    }
#pragma unroll
    for (int off = 8; off <= 32; off <<= 1) {
        wsum += __shfl_xor(wsum, off);
#pragma unroll
        for (int j = 0; j < 8; j++) acc[j] += __shfl_xor(acc[j], off);
    }
    float inv = 1.0f / (wsum + 1e-16f);
    if (lane < 8) {
        const float* bb = b1 + head * 64 + cl * 8;
        unsigned short pk[8];
#pragma unroll
        for (int j = 0; j < 8; j++) pk[j] = f2bf(fmaxf(acc[j] * inv + bb[j], 0.f));
        *((uint4*)(out1b + (size_t)dst * 256 + head * 64 + cl * 8)) = *(const uint4*)pk;
    }
}

// ---------------- pack W2 into MFMA B-fragment layout (bf16) ----------------
__global__ void pack_w2(const float* __restrict__ W2, unsigned short* __restrict__ W2p) {
    int t = threadIdx.x;
    for (int idx = t; idx < 32 * 64; idx += 256) {
        int frag = idx >> 6, lane = idx & 63;
        int ct = frag >> 3, kt = frag & 7;
        int nn = ct * 16 + (lane & 15);
        int kb = kt * 32 + (lane >> 4) * 8;
#pragma unroll
        for (int j = 0; j < 8; j++)
            W2p[frag * 512 + lane * 8 + j] = f2bf(W2[(kb + j) * 64 + nn]);
    }
}

// ---------------- GAT2 transform via MFMA 16x16x32 bf16 ----------------
__global__ void gat2_mfma(const unsigned short* __restrict__ out1b,
                          const unsigned short* __restrict__ W2p,
                          const float* __restrict__ asr, const float* __restrict__ adt,
                          __hip_bfloat16* __restrict__ h2b, float* __restrict__ als,
                          float* __restrict__ ald, int n) {
    __shared__ unsigned short xs[16 * 264];
    __shared__ float aps[4][16];
    __shared__ float apd[4][16];
    int t = threadIdx.x;
    int w = t >> 6, lane = t & 63;
    int base = blockIdx.x * 16;
    for (int i = t; i < 512; i += 256) {
        int nn = i >> 5, c = i & 31;
        uint4 v = make_uint4(0u, 0u, 0u, 0u);
        if (base + nn < n) v = *((const uint4*)(out1b + (size_t)(base + nn) * 256 + c * 8));
        *((uint4*)(xs + nn * 264 + c * 8)) = v;
    }
    __syncthreads();

    int m = lane & 15, quad = lane >> 4;
    floatx4 acc = {0.f, 0.f, 0.f, 0.f};
#pragma unroll
    for (int kt = 0; kt < 8; kt++) {
        bf16x8 a = *((const bf16x8*)(xs + m * 264 + kt * 32 + quad * 8));
        bf16x8 b = *((const bf16x8*)(W2p + (w * 8 + kt) * 512 + lane * 8));
        acc = __builtin_amdgcn_mfma_f32_16x16x32_bf16(a, b, acc, 0, 0, 0);
    }
    int colg = w * 16 + m;
    float a_s = asr[colg], a_d = adt[colg];
    float ps[4], pd[4];
#pragma unroll
    for (int q = 0; q < 4; q++) {
        int node = base + quad * 4 + q;
        if (node < n) h2b[(size_t)node * 64 + colg] = __float2bfloat16(acc[q]);
        ps[q] = acc[q] * a_s;
        pd[q] = acc[q] * a_d;
#pragma unroll
        for (int off = 1; off <= 8; off <<= 1) {
            ps[q] += __shfl_xor(ps[q], off);
            pd[q] += __shfl_xor(pd[q], off);
        }
        if (m == 0) {
            aps[w][quad * 4 + q] = ps[q];
            apd[w][quad * 4 + q] = pd[q];
        }
    }
    __syncthreads();
    if (t < 16 && base + t < n) {
        als[base + t] = aps[0][t] + aps[1][t] + aps[2][t] + aps[3][t];
        ald[base + t] = apd[0][t] + apd[1][t] + apd[2][t] + apd[3][t];
    }
}

// wave per dst; weights precomputed in ew2
__global__ void gat2_aggregate(const unsigned short* __restrict__ h2b,
                               const float* __restrict__ ew2,
                               const int* __restrict__ rowptr,
                               const int* __restrict__ col, const float* __restrict__ b2,
                               float* __restrict__ h2f, int n) {
    int w = threadIdx.x >> 6, lane = threadIdx.x & 63;
    int dst = blockIdx.x * 4 + w;
    if (dst >= n) return;
    int start = rowptr[dst], end = rowptr[dst + 1];

    int eg = lane >> 3;
    int cl = lane & 7;
    float acc[8];
#pragma unroll
    for (int j = 0; j < 8; j++) acc[j] = 0.f;
    float wsum = 0.f;
    for (int ib = start; ib < end; ib += 8) {
        int i = ib + eg;
        float wv = 0.f;
        int s = 0;
        if (i < end) {
            s = col[i];
            wv = ew2[i];
        }
        wsum += wv;
        uint4 hv = *((const uint4*)(h2b + (size_t)s * 64) + cl);
        float l0, u0, l1, u1, l2, u2, l3, u3;
        unpack2(hv.x, l0, u0); unpack2(hv.y, l1, u1);
        unpack2(hv.z, l2, u2); unpack2(hv.w, l3, u3);
        acc[0] += l0 * wv; acc[1] += u0 * wv;
        acc[2] += l1 * wv; acc[3] += u1 * wv;
        acc[4] += l2 * wv; acc[5] += u2 * wv;
        acc[6] += l3 * wv; acc[7] += u3 * wv;
    }
#pragma unroll
    for (int off = 8; off <= 32; off <<= 1) {
        wsum += __shfl_xor(wsum, off);
#pragma unroll
        for (int j = 0; j < 8; j++) acc[j] += __shfl_xor(acc[j], off);
    }
    float inv = 1.0f / (wsum + 1e-16f);
    if (lane < 8) {
        float4 o0, o1;
        const float* bb = b2 + cl * 8;
        o0.x = fmaxf(acc[0] * inv + bb[0], 0.f);
        o0.y = fmaxf(acc[1] * inv + bb[1], 0.f);
        o0.z = fmaxf(acc[2] * inv + bb[2], 0.f);
        o0.w = fmaxf(acc[3] * inv + bb[3], 0.f);
        o1.x = fmaxf(acc[4] * inv + bb[4], 0.f);
        o1.y = fmaxf(acc[5] * inv + bb[5], 0.f);
        o1.z = fmaxf(acc[6] * inv + bb[6], 0.f);
        o1.w = fmaxf(acc[7] * inv + bb[7], 0.f);
        float4* op = (float4*)(h2f + (size_t)dst * 64 + cl * 8);
        op[0] = o0; op[1] = o1;
    }
}

// ---------------- GCN: h2f[N,64] @ Wg[64,32] ----------------
__global__ void gcn_transform(const float* __restrict__ h2f, const float* __restrict__ Wg,
                              float* __restrict__ h3, int n) {
    int idx = blockIdx.x * blockDim.x + threadIdx.x;
    if (idx >= n * 32) return;
    int node = idx >> 5, c = idx & 31;
    float acc = 0.f;
#pragma unroll 8
    for (int k = 0; k < 64; k++) acc += h2f[node * 64 + k] * Wg[k * 32 + c];
    h3[idx] = acc;
}

// wave per dst; full edge norm precomputed in ewg (dinv[s]*dinv[d])
__global__ void gcn_aggregate(const float* __restrict__ h3, const float* __restrict__ ewg,
                              const int* __restrict__ rowptr, const int* __restrict__ col,
                              const float* __restrict__ bg, float* __restrict__ h4, int n) {
    int w = threadIdx.x >> 6, lane = threadIdx.x & 63;
    int dst = blockIdx.x * 4 + w;
    if (dst >= n) return;
    int start = rowptr[dst], end = rowptr[dst + 1];
    int eg = lane >> 3;
    int cl = lane & 7;
    float4 acc = make_float4(0.f, 0.f, 0.f, 0.f);
    for (int ib = start; ib < end; ib += 8) {
        int i = ib + eg;
        float nrm = 0.f;
        int s = 0;
        if (i < end) {
            s = col[i];
            nrm = ewg[i];
        }
        float4 hv = ((const float4*)(h3 + (size_t)s * 32))[cl];
        acc.x += hv.x * nrm; acc.y += hv.y * nrm;
        acc.z += hv.z * nrm; acc.w += hv.w * nrm;
    }
#pragma unroll
    for (int off = 8; off <= 32; off <<= 1) {
        acc.x += __shfl_xor(acc.x, off);
        acc.y += __shfl_xor(acc.y, off);
        acc.z += __shfl_xor(acc.z, off);
        acc.w += __shfl_xor(acc.w, off);
    }
    if (lane < 8) {
        float4 bb = ((const float4*)bg)[cl];
        float4 o;
        o.x = fmaxf(acc.x + bb.x, 0.f);
        o.y = fmaxf(acc.y + bb.y, 0.f);
        o.z = fmaxf(acc.z + bb.z, 0.f);
        o.w = fmaxf(acc.w + bb.w, 0.f);
        ((float4*)(h4 + (size_t)dst * 32))[cl] = o;
    }
}

// ---------------- pooling: block-private LDS partials, sparse flush ------------
__global__ void pool_kernel(const float* __restrict__ h4, const int* __restrict__ batch,
                            float* pooled, float* counts, int n) {
    __shared__ float part[64 * 32];
    __shared__ float pcnt[64];
    int t = threadIdx.x;
    for (int i = t; i < 64 * 32; i += 256) part[i] = 0.f;
    if (t < 64) pcnt[t] = 0.f;
    __syncthreads();
    int chunk = (n + gridDim.x - 1) / gridDim.x;
    int begin = blockIdx.x * chunk;
    int end = begin + chunk; if (end > n) end = n;
    int c = t & 31, r = t >> 5;
    for (int node = begin + r; node < end; node += 8) {
        int g = batch[node];
        atomicAdd(&part[g * 32 + c], h4[(size_t)node * 32 + c]);
        if (c == 0) atomicAdd(&pcnt[g], 1.0f);
    }
    __syncthreads();
    for (int i = t; i < 64 * 32; i += 256) {
        float v = part[i];
        if (v != 0.f) atomicAdd(&pooled[i], v);
    }
    if (t < 64) {
        float v = pcnt[t];
        if (v != 0.f) atomicAdd(&counts[t], v);
    }
}

// ---------------- head: pooled -> anomaly[64] + emb[64,64] ----------------
__global__ void head_kernel(const float* __restrict__ pooled_s, const float* __restrict__ counts,
                            const float* __restrict__ A1, const float* __restrict__ ba1,
                            const float* __restrict__ A2, const float* __restrict__ ba2,
                            const float* __restrict__ A3, const float* __restrict__ ba3,
                            const float* __restrict__ Wemb, const float* __restrict__ bemb,
                            float* __restrict__ out) {
    __shared__ float P[64 * 32];
    __shared__ float Z1[64 * 32];
    __shared__ float Z2[64 * 16];
    int t = threadIdx.x;
    for (int i = t; i < 64 * 32; i += 256) {
        int g = i >> 5;
        P[i] = pooled_s[i] / fmaxf(counts[g], 1.0f);
    }
    __syncthreads();
    for (int i = t; i < 64 * 32; i += 256) {
        int g = i >> 5, c = i & 31;
        float a = ba1[c];
#pragma unroll
        for (int k = 0; k < 32; k++) a += P[g * 32 + k] * A1[k * 32 + c];
        Z1[i] = a > 0.f ? a : 0.f;
    }
    __syncthreads();
    for (int i = t; i < 64 * 16; i += 256) {
        int g = i >> 4, c = i & 15;
        float a = ba2[c];
#pragma unroll
        for (int k = 0; k < 32; k++) a += Z1[g * 32 + k] * A2[k * 16 + c];
        Z2[i] = a > 0.f ? a : 0.f;
    }
    __syncthreads();
    for (int g = t; g < 64; g += 256) {
        float a = ba3[0];
#pragma unroll
        for (int k = 0; k < 16; k++) a += Z2[g * 16 + k] * A3[k];
        out[g] = 1.0f / (1.0f + expf(-a));
    }
    for (int i = t; i < 64 * 64; i += 256) {
        int g = i >> 6, c = i & 63;
        float a = bemb[c];
#pragma unroll
        for (int k = 0; k < 32; k++) a += P[g * 32 + k] * Wemb[k * 64 + c];
        out[64 + i] = tanhf(a);
    }
}

extern "C" void kernel_launch(void* const* d_in, const int* in_sizes, int n_in,
                              void* d_out, int out_size, void* d_ws, size_t ws_size,
                              hipStream_t stream) {
    const float* x    = (const float*)d_in[0];
    const int*   ei   = (const int*)d_in[1];
    const int*   batch= (const int*)d_in[2];
    const float* W1   = (const float*)d_in[3];
    const float* as1  = (const float*)d_in[4];
    const float* ad1  = (const float*)d_in[5];
    const float* b1   = (const float*)d_in[6];
    const float* W2   = (const float*)d_in[7];
    const float* as2  = (const float*)d_in[8];
    const float* ad2  = (const float*)d_in[9];
    const float* b2   = (const float*)d_in[10];
    const float* Wg   = (const float*)d_in[11];
    const float* bg   = (const float*)d_in[12];
    const float* A1   = (const float*)d_in[13];
    const float* ba1  = (const float*)d_in[14];
    const float* A2   = (const float*)d_in[15];
    const float* ba2  = (const float*)d_in[16];
    const float* A3   = (const float*)d_in[17];
    const float* ba3  = (const float*)d_in[18];
    const float* Wemb = (const float*)d_in[19];
    const float* bemb = (const float*)d_in[20];
    float* out = (float*)d_out;

    const int N = in_sizes[0] / 32;
    const int E = in_sizes[1] / 2;
    const int ET = E + N;

    char* base = (char*)d_ws;
    size_t off = 0;
    auto take = [&](size_t bytes) -> char* {
        char* p = base + off;
        off = (off + bytes + 255) & ~(size_t)255;
        return p;
    };
    int*   deg    = (int*)take((size_t)N * 4);
    int*   rowptr = (int*)take((size_t)(N + 1) * 4);
    int*   cursor = (int*)take((size_t)N * 4);
    int*   col    = (int*)take((size_t)ET * 4);
    int*   edst   = (int*)take((size_t)ET * 4);
    float* ewbuf  = (float*)take((size_t)ET * 16);   // ew4; later ew2+ewg
    float* dinv   = (float*)take((size_t)N * 4);
    float* als1   = (float*)take((size_t)N * 16);
    float* ald1   = (float*)take((size_t)N * 16);
    int*   bsum   = (int*)take(256 * 4);
    int*   boff   = (int*)take(256 * 4);
    unsigned short* W2p = (unsigned short*)take(32 * 512 * 2);   // packed B-frags
    char*  big1   = take((size_t)N * 512);       // h1b bf16; later h2b/h2f/als2/ald2
    char*  big2   = take((size_t)N * 1024);      // out1b bf16 + h3/h4
    float* pooled = (float*)take(64 * 32 * 4);
    float* counts = (float*)take(64 * 4);

    float* ew4 = ewbuf;
    float* ew2 = ewbuf;                      // reuse after gat1_aggregate
    float* ewg = ewbuf + (size_t)ET;

    __hip_bfloat16* h1b = (__hip_bfloat16*)big1;
    __hip_bfloat16* h2b = (__hip_bfloat16*)big1;                  // after h1b dead
    float* h2f  = (float*)(big1 + (size_t)N * 128);
    float* als2 = (float*)(big1 + (size_t)N * 384);
    float* ald2 = (float*)(big1 + (size_t)N * 388);
    unsigned short* out1b = (unsigned short*)big2;                // N*512 B
    float* h3   = (float*)(big2 + (size_t)N * 512);               // N*128 B
    float* h4   = (float*)(big2 + (size_t)N * 640);               // N*128 B

    int gN = (N + 255) / 256;
    int gE = (ET + 255) / 256;
    int gN4 = (N + 3) / 4;
    int gN16 = (N + 15) / 16;
    int nquads = (N + 3) / 4;
    int gAgg1 = ((nquads + 1) / 2) * 8;   // head-partitioned grid (4 dst x 1 head per block)

    zero_init<<<gN, 256, 0, stream>>>(deg, pooled, counts, N);
    count_edges<<<gE, 256, 0, stream>>>(ei, E, N, deg);
    deg_dinv_bsum<<<gN, 256, 0, stream>>>(deg, dinv, bsum, N);
    scan_bsum<<<1, 256, 0, stream>>>(bsum, boff, rowptr, gN, N);
    write_rowptr<<<gN, 256, 0, stream>>>(deg, boff, rowptr, cursor, N);
    pack_w2<<<1, 256, 0, stream>>>(W2, W2p);

    gat1_transform<<<gN16, 256, 0, stream>>>(x, W1, as1, ad1, h1b, als1, ald1, N);
    fill_edges<<<gE, 256, 0, stream>>>(ei, E, N, cursor, col, edst, ew4, als1, ald1);
    gat1_aggregate<<<gAgg1, 256, 0, stream>>>((const unsigned short*)h1b, ew4,
                                              rowptr, col, b1, out1b, N);

    gat2_mfma<<<gN16, 256, 0, stream>>>(out1b, W2p, as2, ad2, h2b, als2, ald2, N);
    edge_w2<<<gE, 256, 0, stream>>>(col, edst, als2, ald2, dinv, ew2, ewg, ET);
    gat2_aggregate<<<gN4, 256, 0, stream>>>((const unsigned short*)h2b, ew2,
                                            rowptr, col, b2, h2f, N);

    gcn_transform<<<(N * 32 + 255) / 256, 256, 0, stream>>>(h2f, Wg, h3, N);
    gcn_aggregate<<<gN4, 256, 0, stream>>>(h3, ewg, rowptr, col, bg, h4, N);
    pool_kernel<<<256, 256, 0, stream>>>(h4, batch, pooled, counts, N);

    head_kernel<<<1, 256, 0, stream>>>(pooled, counts, A1, ba1, A2, ba2, A3, ba3,
                                       Wemb, bemb, out);
}

// Round 15
// 261.534 us; speedup vs baseline: 1.1608x; 1.0104x over previous
//
#include <hip/hip_runtime.h>
#include <hip/hip_bf16.h>

#define NEG 0.2f

typedef short bf16x8 __attribute__((ext_vector_type(8)));
typedef float floatx4 __attribute__((ext_vector_type(4)));

__device__ __forceinline__ float leaky(float v) { return v > 0.f ? v : NEG * v; }

__device__ __forceinline__ void unpack2(unsigned w, float& lo, float& hi) {
    union { unsigned u; float f; } a, b;
    a.u = w << 16;
    b.u = w & 0xffff0000u;
    lo = a.f; hi = b.f;
}

__device__ __forceinline__ unsigned short f2bf(float f) {
    union { float f; unsigned u; } v; v.f = f;
    unsigned r = v.u + 0x7fff + ((v.u >> 16) & 1);
    return (unsigned short)(r >> 16);
}

// ---------------- init ----------------
__global__ void zero_init(int* deg, float* pooled, float* counts, int n) {
    int i = blockIdx.x * blockDim.x + threadIdx.x;
    if (i < n) deg[i] = 0;
    if (i < 64 * 32) pooled[i] = 0.f;
    if (i < 64) counts[i] = 0.f;
}

// ---------------- CSR build ----------------
__global__ void count_edges(const int* __restrict__ ei, int E, int n, int* deg) {
    int i = blockIdx.x * blockDim.x + threadIdx.x;
    int tot = E + n;
    if (i < tot) {
        int dst = (i < E) ? ei[E + i] : (i - E);
        atomicAdd(&deg[dst], 1);
    }
}

__global__ void deg_dinv_bsum(const int* __restrict__ deg, float* __restrict__ dinv,
                              int* __restrict__ bsum, int n) {
    __shared__ int red[256];
    int t = threadIdx.x;
    int i = blockIdx.x * 256 + t;
    int d = (i < n) ? deg[i] : 0;
    if (i < n) dinv[i] = rsqrtf(fmaxf((float)d, 1.0f));
    red[t] = d;
    __syncthreads();
    for (int off = 128; off; off >>= 1) {
        if (t < off) red[t] += red[t + off];
        __syncthreads();
    }
    if (t == 0) bsum[blockIdx.x] = red[0];
}

__global__ void scan_bsum(const int* __restrict__ bsum, int* __restrict__ boff,
                          int* __restrict__ rowptr, int nb, int n) {
    __shared__ int s[256];
    int t = threadIdx.x;
    int own = (t < nb) ? bsum[t] : 0;
    s[t] = own;
    __syncthreads();
    for (int off = 1; off < 256; off <<= 1) {
        int v = (t >= off) ? s[t - off] : 0;
        __syncthreads();
        s[t] += v;
        __syncthreads();
    }
    if (t < nb) boff[t] = s[t] - own;
    if (t == 255) rowptr[n] = s[255];
}

__global__ void write_rowptr(const int* __restrict__ deg, const int* __restrict__ boff,
                             int* __restrict__ rowptr, int* __restrict__ cursor, int n) {
    __shared__ int s[256];
    int t = threadIdx.x;
    int i = blockIdx.x * 256 + t;
    int d = (i < n) ? deg[i] : 0;
    s[t] = d;
    __syncthreads();
    for (int off = 1; off < 256; off <<= 1) {
        int v = (t >= off) ? s[t - off] : 0;
        __syncthreads();
        s[t] += v;
        __syncthreads();
    }
    if (i < n) {
        int r = boff[blockIdx.x] + s[t] - d;
        rowptr[i] = r;
        cursor[i] = r;
    }
}

// runs AFTER gat1_transform: precomputes per-edge GAT1 weights (4 heads) + edst
__global__ void fill_edges(const int* __restrict__ ei, int E, int n, int* cursor,
                           int* __restrict__ col, int* __restrict__ edst,
                           float* __restrict__ ew4,
                           const float* __restrict__ als1, const float* __restrict__ ald1) {
    int i = blockIdx.x * blockDim.x + threadIdx.x;
    int tot = E + n;
    if (i < tot) {
        int src, dst;
        if (i < E) { src = ei[i]; dst = ei[E + i]; }
        else { src = i - E; dst = i - E; }
        int pos = atomicAdd(&cursor[dst], 1);
        col[pos] = src;
        edst[pos] = dst;
        float4 as = ((const float4*)als1)[src];
        float4 ad = ((const float4*)ald1)[dst];
        float4 w;
        w.x = __expf(leaky(as.x + ad.x));
        w.y = __expf(leaky(as.y + ad.y));
        w.z = __expf(leaky(as.z + ad.z));
        w.w = __expf(leaky(as.w + ad.w));
        ((float4*)ew4)[pos] = w;
    }
}

// after gat2_mfma: per-edge GAT2 weight + fused GCN norm
__global__ void edge_w2(const int* __restrict__ col, const int* __restrict__ edst,
                        const float* __restrict__ als2, const float* __restrict__ ald2,
                        const float* __restrict__ dinv,
                        float* __restrict__ ew2, float* __restrict__ ewg, int et) {
    int i = blockIdx.x * blockDim.x + threadIdx.x;
    if (i < et) {
        int s = col[i], d = edst[i];
        ew2[i] = __expf(leaky(als2[s] + ald2[d]));
        ewg[i] = dinv[s] * dinv[d];
    }
}

// ---------------- GAT1: x[N,32] @ W1[32,256]; h1 stored bf16 ----
__global__ void gat1_transform(const float* __restrict__ x, const float* __restrict__ W1,
                               const float* __restrict__ asr, const float* __restrict__ adt,
                               __hip_bfloat16* __restrict__ h1b, float* __restrict__ als,
                               float* __restrict__ ald, int n) {
    __shared__ float xr[16][32];
    int t = threadIdx.x;  // 256
    int base = blockIdx.x * 16;
    float w1r[32];
#pragma unroll
    for (int j = 0; j < 32; j++) w1r[j] = W1[j * 256 + t];
    if (t < 128) {
        int node = t >> 3;
        float4 v = make_float4(0.f, 0.f, 0.f, 0.f);
        if (base + node < n) v = ((const float4*)(x + (size_t)base * 32))[t];
        ((float4*)&xr[0][0])[t] = v;
    }
    __syncthreads();
    int head = t >> 6, lane = t & 63;
    float a_s = asr[t];
    float a_d = adt[t];
    for (int nn = 0; nn < 16; nn++) {
        int node = base + nn;
        float acc0 = 0.f, acc1 = 0.f, acc2 = 0.f, acc3 = 0.f;
#pragma unroll
        for (int j = 0; j < 32; j += 4) {
            acc0 += xr[nn][j]     * w1r[j];
            acc1 += xr[nn][j + 1] * w1r[j + 1];
            acc2 += xr[nn][j + 2] * w1r[j + 2];
            acc3 += xr[nn][j + 3] * w1r[j + 3];
        }
        float acc = (acc0 + acc1) + (acc2 + acc3);
        if (node < n) h1b[(size_t)node * 256 + t] = __float2bfloat16(acc);
        float ps = acc * a_s;
        float pd = acc * a_d;
#pragma unroll
        for (int off = 32; off; off >>= 1) {
            ps += __shfl_down(ps, off);
            pd += __shfl_down(pd, off);
        }
        if (node < n && lane == 0) { als[node * 4 + head] = ps; ald[node * 4 + head] = pd; }
    }
}

// XCD-aware head partitioning (R13 win): block = ONE head x 4 dsts; head =
// (blockIdx&7)>>1 pins each head's 2.56 MB h1b slice into 2 XCDs' L2.
// Edge loop unrolled 2x: 16 edges/iter, two uint4 gathers in flight.
__global__ void gat1_aggregate(const unsigned short* __restrict__ h1b,
                               const float* __restrict__ ew4,
                               const int* __restrict__ rowptr,
                               const int* __restrict__ col, const float* __restrict__ b1,
                               unsigned short* __restrict__ out1b, int n) {
    int head = (blockIdx.x & 7) >> 1;
    int quad = (blockIdx.x >> 3) * 2 + (blockIdx.x & 1);
    int w = threadIdx.x >> 6, lane = threadIdx.x & 63;
    int dst = quad * 4 + w;
    if (dst >= n) return;
    int start = rowptr[dst], end = rowptr[dst + 1];

    int eg = lane >> 3;
    int cl = lane & 7;
    float acc[8];
#pragma unroll
    for (int j = 0; j < 8; j++) acc[j] = 0.f;
    float wsum = 0.f;
    for (int ib = start; ib < end; ib += 16) {
        int i0 = ib + eg, i1 = ib + 8 + eg;
        float w0 = 0.f, w1 = 0.f;
        int s0 = 0, s1 = 0;
        if (i0 < end) { s0 = col[i0]; w0 = ew4[i0 * 4 + head]; }
        if (i1 < end) { s1 = col[i1]; w1 = ew4[i1 * 4 + head]; }
        uint4 hv0 = *((const uint4*)(h1b + (size_t)s0 * 256 + head * 64) + cl);
        uint4 hv1 = *((const uint4*)(h1b + (size_t)s1 * 256 + head * 64) + cl);
        wsum += w0 + w1;
        float l0, u0, l1, u1, l2, u2, l3, u3;
        unpack2(hv0.x, l0, u0); unpack2(hv0.y, l1, u1);
        unpack2(hv0.z, l2, u2); unpack2(hv0.w, l3, u3);
        acc[0] += l0 * w0; acc[1] += u0 * w0;
        acc[2] += l1 * w0; acc[3] += u1 * w0;
        acc[4] += l2 * w0; acc[5] += u2 * w0;
        acc[6] += l3 * w0; acc[7] += u3 * w0;
        unpack2(hv1.x, l0, u0); unpack2(hv1.y, l1, u1);
        unpack2(hv1.z, l2, u2); unpack2(hv1.w, l3, u3);
        acc[0] += l0 * w1; acc[1] += u0 * w1;
        acc[2] += l1 * w1; acc[3] += u1 * w1;
        acc[4] += l2 * w1; acc[5] += u2 * w1;
        acc[6] += l3 * w1; acc[7] += u3 * w1;
    }
#pragma unroll
    for (int off = 8; off <= 32; off <<= 1) {
        wsum += __shfl_xor(wsum, off);
#pragma unroll
        for (int j = 0; j < 8; j++) acc[j] += __shfl_xor(acc[j], off);
    }
    float inv = 1.0f / (wsum + 1e-16f);
    if (lane < 8) {
        const float* bb = b1 + head * 64 + cl * 8;
        unsigned short pk[8];
#pragma unroll
        for (int j = 0; j < 8; j++) pk[j] = f2bf(fmaxf(acc[j] * inv + bb[j], 0.f));
        *((uint4*)(out1b + (size_t)dst * 256 + head * 64 + cl * 8)) = *(const uint4*)pk;
    }
}

// ---------------- pack W2 into MFMA B-fragment layout (bf16) ----------------
__global__ void pack_w2(const float* __restrict__ W2, unsigned short* __restrict__ W2p) {
    int t = threadIdx.x;
    for (int idx = t; idx < 32 * 64; idx += 256) {
        int frag = idx >> 6, lane = idx & 63;
        int ct = frag >> 3, kt = frag & 7;
        int nn = ct * 16 + (lane & 15);
        int kb = kt * 32 + (lane >> 4) * 8;
#pragma unroll
        for (int j = 0; j < 8; j++)
            W2p[frag * 512 + lane * 8 + j] = f2bf(W2[(kb + j) * 64 + nn]);
    }
}

// ---------------- GAT2 transform via MFMA 16x16x32 bf16 ----------------
__global__ void gat2_mfma(const unsigned short* __restrict__ out1b,
                          const unsigned short* __restrict__ W2p,
                          const float* __restrict__ asr, const float* __restrict__ adt,
                          __hip_bfloat16* __restrict__ h2b, float* __restrict__ als,
                          float* __restrict__ ald, int n) {
    __shared__ unsigned short xs[16 * 264];
    __shared__ float aps[4][16];
    __shared__ float apd[4][16];
    int t = threadIdx.x;
    int w = t >> 6, lane = t & 63;
    int base = blockIdx.x * 16;
    for (int i = t; i < 512; i += 256) {
        int nn = i >> 5, c = i & 31;
        uint4 v = make_uint4(0u, 0u, 0u, 0u);
        if (base + nn < n) v = *((const uint4*)(out1b + (size_t)(base + nn) * 256 + c * 8));
        *((uint4*)(xs + nn * 264 + c * 8)) = v;
    }
    __syncthreads();

    int m = lane & 15, quad = lane >> 4;
    floatx4 acc = {0.f, 0.f, 0.f, 0.f};
#pragma unroll
    for (int kt = 0; kt < 8; kt++) {
        bf16x8 a = *((const bf16x8*)(xs + m * 264 + kt * 32 + quad * 8));
        bf16x8 b = *((const bf16x8*)(W2p + (w * 8 + kt) * 512 + lane * 8));
        acc = __builtin_amdgcn_mfma_f32_16x16x32_bf16(a, b, acc, 0, 0, 0);
    }
    int colg = w * 16 + m;
    float a_s = asr[colg], a_d = adt[colg];
    float ps[4], pd[4];
#pragma unroll
    for (int q = 0; q < 4; q++) {
        int node = base + quad * 4 + q;
        if (node < n) h2b[(size_t)node * 64 + colg] = __float2bfloat16(acc[q]);
        ps[q] = acc[q] * a_s;
        pd[q] = acc[q] * a_d;
#pragma unroll
        for (int off = 1; off <= 8; off <<= 1) {
            ps[q] += __shfl_xor(ps[q], off);
            pd[q] += __shfl_xor(pd[q], off);
        }
        if (m == 0) {
            aps[w][quad * 4 + q] = ps[q];
            apd[w][quad * 4 + q] = pd[q];
        }
    }
    __syncthreads();
    if (t < 16 && base + t < n) {
        als[base + t] = aps[0][t] + aps[1][t] + aps[2][t] + aps[3][t];
        ald[base + t] = apd[0][t] + apd[1][t] + apd[2][t] + apd[3][t];
    }
}

// wave per dst; GAT2 aggregate FUSED with GCN transform:
// epilogue bounces relu(h2f) through per-wave LDS and computes
// h3[dst] = relu(h2f) @ Wg (Wg staged in LDS; lane c hits bank c - no conflict).
__global__ void gat2_agg_gcn(const unsigned short* __restrict__ h2b,
                             const float* __restrict__ ew2,
                             const int* __restrict__ rowptr,
                             const int* __restrict__ col, const float* __restrict__ b2,
                             const float* __restrict__ Wg,
                             float* __restrict__ h3, int n) {
    __shared__ float WgL[64 * 32];     // 8 KB
    __shared__ float h2L[4][64];       // 1 KB, per-wave slot
    int t = threadIdx.x;
    for (int i = t; i < 64 * 32; i += 256) WgL[i] = Wg[i];
    __syncthreads();

    int w = t >> 6, lane = t & 63;
    int dst = blockIdx.x * 4 + w;
    if (dst >= n) return;
    int start = rowptr[dst], end = rowptr[dst + 1];

    int eg = lane >> 3;
    int cl = lane & 7;
    float acc[8];
#pragma unroll
    for (int j = 0; j < 8; j++) acc[j] = 0.f;
    float wsum = 0.f;
    for (int ib = start; ib < end; ib += 8) {
        int i = ib + eg;
        float wv = 0.f;
        int s = 0;
        if (i < end) {
            s = col[i];
            wv = ew2[i];
        }
        wsum += wv;
        uint4 hv = *((const uint4*)(h2b + (size_t)s * 64) + cl);
        float l0, u0, l1, u1, l2, u2, l3, u3;
        unpack2(hv.x, l0, u0); unpack2(hv.y, l1, u1);
        unpack2(hv.z, l2, u2); unpack2(hv.w, l3, u3);
        acc[0] += l0 * wv; acc[1] += u0 * wv;
        acc[2] += l1 * wv; acc[3] += u1 * wv;
        acc[4] += l2 * wv; acc[5] += u2 * wv;
        acc[6] += l3 * wv; acc[7] += u3 * wv;
    }
#pragma unroll
    for (int off = 8; off <= 32; off <<= 1) {
        wsum += __shfl_xor(wsum, off);
#pragma unroll
        for (int j = 0; j < 8; j++) acc[j] += __shfl_xor(acc[j], off);
    }
    float inv = 1.0f / (wsum + 1e-16f);
    // relu(h2f) -> per-wave LDS (lanes 0..7 hold channels cl*8..cl*8+7)
    if (lane < 8) {
        const float* bb = b2 + cl * 8;
#pragma unroll
        for (int j = 0; j < 8; j++)
            h2L[w][cl * 8 + j] = fmaxf(acc[j] * inv + bb[j], 0.f);
    }
    // within-wave LDS write->read: compiler inserts lgkmcnt wait; no barrier needed
    if (lane < 32) {
        float s0 = 0.f, s1 = 0.f;
#pragma unroll
        for (int k = 0; k < 64; k += 2) {
            s0 += h2L[w][k]     * WgL[k * 32 + lane];
            s1 += h2L[w][k + 1] * WgL[(k + 1) * 32 + lane];
        }
        h3[(size_t)dst * 32 + lane] = s0 + s1;
    }
}

// wave per dst; full edge norm precomputed in ewg (dinv[s]*dinv[d])
__global__ void gcn_aggregate(const float* __restrict__ h3, const float* __restrict__ ewg,
                              const int* __restrict__ rowptr, const int* __restrict__ col,
                              const float* __restrict__ bg, float* __restrict__ h4, int n) {
    int w = threadIdx.x >> 6, lane = threadIdx.x & 63;
    int dst = blockIdx.x * 4 + w;
    if (dst >= n) return;
    int start = rowptr[dst], end = rowptr[dst + 1];
    int eg = lane >> 3;
    int cl = lane & 7;
    float4 acc = make_float4(0.f, 0.f, 0.f, 0.f);
    for (int ib = start; ib < end; ib += 8) {
        int i = ib + eg;
        float nrm = 0.f;
        int s = 0;
        if (i < end) {
            s = col[i];
            nrm = ewg[i];
        }
        float4 hv = ((const float4*)(h3 + (size_t)s * 32))[cl];
        acc.x += hv.x * nrm; acc.y += hv.y * nrm;
        acc.z += hv.z * nrm; acc.w += hv.w * nrm;
    }
#pragma unroll
    for (int off = 8; off <= 32; off <<= 1) {
        acc.x += __shfl_xor(acc.x, off);
        acc.y += __shfl_xor(acc.y, off);
        acc.z += __shfl_xor(acc.z, off);
        acc.w += __shfl_xor(acc.w, off);
    }
    if (lane < 8) {
        float4 bb = ((const float4*)bg)[cl];
        float4 o;
        o.x = fmaxf(acc.x + bb.x, 0.f);
        o.y = fmaxf(acc.y + bb.y, 0.f);
        o.z = fmaxf(acc.z + bb.z, 0.f);
        o.w = fmaxf(acc.w + bb.w, 0.f);
        ((float4*)(h4 + (size_t)dst * 32))[cl] = o;
    }
}

// ---------------- pooling: block-private LDS partials, sparse flush ------------
__global__ void pool_kernel(const float* __restrict__ h4, const int* __restrict__ batch,
                            float* pooled, float* counts, int n) {
    __shared__ float part[64 * 32];
    __shared__ float pcnt[64];
    int t = threadIdx.x;
    for (int i = t; i < 64 * 32; i += 256) part[i] = 0.f;
    if (t < 64) pcnt[t] = 0.f;
    __syncthreads();
    int chunk = (n + gridDim.x - 1) / gridDim.x;
    int begin = blockIdx.x * chunk;
    int end = begin + chunk; if (end > n) end = n;
    int c = t & 31, r = t >> 5;
    for (int node = begin + r; node < end; node += 8) {
        int g = batch[node];
        atomicAdd(&part[g * 32 + c], h4[(size_t)node * 32 + c]);
        if (c == 0) atomicAdd(&pcnt[g], 1.0f);
    }
    __syncthreads();
    for (int i = t; i < 64 * 32; i += 256) {
        float v = part[i];
        if (v != 0.f) atomicAdd(&pooled[i], v);
    }
    if (t < 64) {
        float v = pcnt[t];
        if (v != 0.f) atomicAdd(&counts[t], v);
    }
}

// ---------------- head: pooled -> anomaly[64] + emb[64,64] ----------------
__global__ void head_kernel(const float* __restrict__ pooled_s, const float* __restrict__ counts,
                            const float* __restrict__ A1, const float* __restrict__ ba1,
                            const float* __restrict__ A2, const float* __restrict__ ba2,
                            const float* __restrict__ A3, const float* __restrict__ ba3,
                            const float* __restrict__ Wemb, const float* __restrict__ bemb,
                            float* __restrict__ out) {
    __shared__ float P[64 * 32];
    __shared__ float Z1[64 * 32];
    __shared__ float Z2[64 * 16];
    int t = threadIdx.x;
    for (int i = t; i < 64 * 32; i += 256) {
        int g = i >> 5;
        P[i] = pooled_s[i] / fmaxf(counts[g], 1.0f);
    }
    __syncthreads();
    for (int i = t; i < 64 * 32; i += 256) {
        int g = i >> 5, c = i & 31;
        float a = ba1[c];
#pragma unroll
        for (int k = 0; k < 32; k++) a += P[g * 32 + k] * A1[k * 32 + c];
        Z1[i] = a > 0.f ? a : 0.f;
    }
    __syncthreads();
    for (int i = t; i < 64 * 16; i += 256) {
        int g = i >> 4, c = i & 15;
        float a = ba2[c];
#pragma unroll
        for (int k = 0; k < 32; k++) a += Z1[g * 32 + k] * A2[k * 16 + c];
        Z2[i] = a > 0.f ? a : 0.f;
    }
    __syncthreads();
    for (int g = t; g < 64; g += 256) {
        float a = ba3[0];
#pragma unroll
        for (int k = 0; k < 16; k++) a += Z2[g * 16 + k] * A3[k];
        out[g] = 1.0f / (1.0f + expf(-a));
    }
    for (int i = t; i < 64 * 64; i += 256) {
        int g = i >> 6, c = i & 63;
        float a = bemb[c];
#pragma unroll
        for (int k = 0; k < 32; k++) a += P[g * 32 + k] * Wemb[k * 64 + c];
        out[64 + i] = tanhf(a);
    }
}

extern "C" void kernel_launch(void* const* d_in, const int* in_sizes, int n_in,
                              void* d_out, int out_size, void* d_ws, size_t ws_size,
                              hipStream_t stream) {
    const float* x    = (const float*)d_in[0];
    const int*   ei   = (const int*)d_in[1];
    const int*   batch= (const int*)d_in[2];
    const float* W1   = (const float*)d_in[3];
    const float* as1  = (const float*)d_in[4];
    const float* ad1  = (const float*)d_in[5];
    const float* b1   = (const float*)d_in[6];
    const float* W2   = (const float*)d_in[7];
    const float* as2  = (const float*)d_in[8];
    const float* ad2  = (const float*)d_in[9];
    const float* b2   = (const float*)d_in[10];
    const float* Wg   = (const float*)d_in[11];
    const float* bg   = (const float*)d_in[12];
    const float* A1   = (const float*)d_in[13];
    const float* ba1  = (const float*)d_in[14];
    const float* A2   = (const float*)d_in[15];
    const float* ba2  = (const float*)d_in[16];
    const float* A3   = (const float*)d_in[17];
    const float* ba3  = (const float*)d_in[18];
    const float* Wemb = (const float*)d_in[19];
    const float* bemb = (const float*)d_in[20];
    float* out = (float*)d_out;

    const int N = in_sizes[0] / 32;
    const int E = in_sizes[1] / 2;
    const int ET = E + N;

    char* base = (char*)d_ws;
    size_t off = 0;
    auto take = [&](size_t bytes) -> char* {
        char* p = base + off;
        off = (off + bytes + 255) & ~(size_t)255;
        return p;
    };
    int*   deg    = (int*)take((size_t)N * 4);
    int*   rowptr = (int*)take((size_t)(N + 1) * 4);
    int*   cursor = (int*)take((size_t)N * 4);
    int*   col    = (int*)take((size_t)ET * 4);
    int*   edst   = (int*)take((size_t)ET * 4);
    float* ewbuf  = (float*)take((size_t)ET * 16);   // ew4; later ew2+ewg
    float* dinv   = (float*)take((size_t)N * 4);
    float* als1   = (float*)take((size_t)N * 16);
    float* ald1   = (float*)take((size_t)N * 16);
    int*   bsum   = (int*)take(256 * 4);
    int*   boff   = (int*)take(256 * 4);
    unsigned short* W2p = (unsigned short*)take(32 * 512 * 2);
    char*  big1   = take((size_t)N * 512);       // h1b bf16; later h2b/h3/als2/ald2
    char*  big2   = take((size_t)N * 1024);      // out1b bf16 + h4
    float* pooled = (float*)take(64 * 32 * 4);
    float* counts = (float*)take(64 * 4);

    float* ew4 = ewbuf;
    float* ew2 = ewbuf;                      // reuse after gat1_aggregate
    float* ewg = ewbuf + (size_t)ET;

    __hip_bfloat16* h1b = (__hip_bfloat16*)big1;
    __hip_bfloat16* h2b = (__hip_bfloat16*)big1;                  // after h1b dead
    float* h3   = (float*)(big1 + (size_t)N * 128);               // N*128 B
    float* als2 = (float*)(big1 + (size_t)N * 384);
    float* ald2 = (float*)(big1 + (size_t)N * 388);
    unsigned short* out1b = (unsigned short*)big2;                // N*512 B
    float* h4   = (float*)(big2 + (size_t)N * 512);               // N*128 B

    int gN = (N + 255) / 256;
    int gE = (ET + 255) / 256;
    int gN4 = (N + 3) / 4;
    int gN16 = (N + 15) / 16;
    int nquads = (N + 3) / 4;
    int gAgg1 = ((nquads + 1) / 2) * 8;

    zero_init<<<gN, 256, 0, stream>>>(deg, pooled, counts, N);
    count_edges<<<gE, 256, 0, stream>>>(ei, E, N, deg);
    deg_dinv_bsum<<<gN, 256, 0, stream>>>(deg, dinv, bsum, N);
    scan_bsum<<<1, 256, 0, stream>>>(bsum, boff, rowptr, gN, N);
    write_rowptr<<<gN, 256, 0, stream>>>(deg, boff, rowptr, cursor, N);
    pack_w2<<<1, 256, 0, stream>>>(W2, W2p);

    gat1_transform<<<gN16, 256, 0, stream>>>(x, W1, as1, ad1, h1b, als1, ald1, N);
    fill_edges<<<gE, 256, 0, stream>>>(ei, E, N, cursor, col, edst, ew4, als1, ald1);
    gat1_aggregate<<<gAgg1, 256, 0, stream>>>((const unsigned short*)h1b, ew4,
                                              rowptr, col, b1, out1b, N);

    gat2_mfma<<<gN16, 256, 0, stream>>>(out1b, W2p, as2, ad2, h2b, als2, ald2, N);
    edge_w2<<<gE, 256, 0, stream>>>(col, edst, als2, ald2, dinv, ew2, ewg, ET);
    gat2_agg_gcn<<<gN4, 256, 0, stream>>>((const unsigned short*)h2b, ew2,
                                          rowptr, col, b2, Wg, h3, N);

    gcn_aggregate<<<gN4, 256, 0, stream>>>(h3, ewg, rowptr, col, bg, h4, N);
    pool_kernel<<<256, 256, 0, stream>>>(h4, batch, pooled, counts, N);

    head_kernel<<<1, 256, 0, stream>>>(pooled, counts, A1, ba1, A2, ba2, A3, ba3,
                                       Wemb, bemb, out);
}